// Round 9
// baseline (1169.064 us; speedup 1.0000x reference)
//
#include <hip/hip_runtime.h>
#include <hip/hip_bf16.h>
#include <stdint.h>

// ---------------------------------------------------------------------------
// TopKAutoEncoder forward, MI355X.
// acts = (x - pre_bias) @ W_enc + latent_bias   [16384 x 4096]
// top-64/row (exact selection vs ref), relu, @ W_dec + pre_bias.
//
// GEMM: R3 measured-best: 256x256 tile, BK=32, 4-deep LDS pipeline, counted
// vmcnt(8), chunk-XOR swizzle f(r)=(r>>1)&3 (0 bank conflicts), XCD block
// swizzle, setprio.
// R9: topk_full = histogram classify (8192 x 0.125 bins, MARGIN=0.1875)
// FUSED with the fp64 boundary rescue (zone in LDS, wave-per-candidate).
// bf16 sparse reconstruct with XCD-L2-resident W_dec slabs.
// ---------------------------------------------------------------------------

typedef _Float16 half8 __attribute__((ext_vector_type(8)));
typedef float f32x4 __attribute__((ext_vector_type(4)));
typedef unsigned short ushort8 __attribute__((ext_vector_type(8)));

#define B_ROWS 16384
#define D_DIM  4096
#define TOPK   64
#define MARGIN 0.1875f
#define NTILES (D_DIM / 32)

__device__ __forceinline__ void gload_lds16(const void* g, void* l) {
  __builtin_amdgcn_global_load_lds(
      (const __attribute__((address_space(1))) unsigned int*)g,
      (__attribute__((address_space(3))) unsigned int*)l, 16, 0, 0);
}

__device__ __forceinline__ unsigned short f2bf(float f) {
  unsigned u = __float_as_uint(f);
  unsigned r = (u + 0x7fffu + ((u >> 16) & 1u)) >> 16;
  return (unsigned short)r;
}

// --------------------------- conversion kernels ----------------------------

__global__ __launch_bounds__(256) void conv_x(
    const float* __restrict__ x, const float* __restrict__ pre_bias,
    _Float16* __restrict__ Xh) {
  size_t g = ((size_t)blockIdx.x * 256 + threadIdx.x) * 8;
  int col = (int)(g & (D_DIM - 1));
  float4 a = *(const float4*)(x + g);
  float4 b = *(const float4*)(x + g + 4);
  float4 p = *(const float4*)(pre_bias + col);
  float4 q = *(const float4*)(pre_bias + col + 4);
  half8 h;
  h[0] = (_Float16)(a.x - p.x); h[1] = (_Float16)(a.y - p.y);
  h[2] = (_Float16)(a.z - p.z); h[3] = (_Float16)(a.w - p.w);
  h[4] = (_Float16)(b.x - q.x); h[5] = (_Float16)(b.y - q.y);
  h[6] = (_Float16)(b.z - q.z); h[7] = (_Float16)(b.w - q.w);
  *(half8*)(Xh + g) = h;
}

// W_enc [K][N] fp32 -> WhT [N][K] fp16  AND WT [N][K] fp32 (for fp64 rescue)
__global__ __launch_bounds__(256) void transp_w(
    const float* __restrict__ W, _Float16* __restrict__ WhT,
    float* __restrict__ WT) {
  __shared__ float tile[64][65];
  int bx = blockIdx.x, by = blockIdx.y;
  int tx = threadIdx.x & 63, ty4 = threadIdx.x >> 6;
  #pragma unroll 4
  for (int i = 0; i < 16; ++i) {
    int r = ty4 * 16 + i;
    tile[r][tx] = W[(size_t)(by * 64 + r) * D_DIM + bx * 64 + tx];
  }
  __syncthreads();
  #pragma unroll 4
  for (int i = 0; i < 16; ++i) {
    int r = ty4 * 16 + i;
    float v = tile[tx][r];
    size_t o = (size_t)(bx * 64 + r) * D_DIM + by * 64 + tx;
    WT[o] = v;
    WhT[o] = (_Float16)v;
  }
}

__global__ __launch_bounds__(256) void conv_wd(
    const float* __restrict__ W, unsigned short* __restrict__ o) {
  size_t g = ((size_t)blockIdx.x * 256 + threadIdx.x) * 8;
  float4 a = *(const float4*)(W + g);
  float4 b = *(const float4*)(W + g + 4);
  ushort8 v;
  v[0] = f2bf(a.x); v[1] = f2bf(a.y); v[2] = f2bf(a.z); v[3] = f2bf(a.w);
  v[4] = f2bf(b.x); v[5] = f2bf(b.y); v[6] = f2bf(b.z); v[7] = f2bf(b.w);
  *(ushort8*)(o + g) = v;
}

// ------------------------------- fp16 GEMM (R3 verbatim) -------------------

#define TILE_BODY(T, VMSTR)                                                    \
  do {                                                                         \
    asm volatile("s_waitcnt " VMSTR ::: "memory");                             \
    __builtin_amdgcn_s_barrier();                                              \
    asm volatile("" ::: "memory");                                             \
    const int tt3 = (T) + 3;                                                   \
    if (tt3 < NTILES) {                                                        \
      const int bo = (tt3 & 3) * 8192;                                         \
      const int kk = tt3 * 32;                                                 \
      gload_lds16(aSrc0 + kk, AsB + bo + dst0);                                \
      gload_lds16(aSrc1 + kk, AsB + bo + dst1);                                \
    }                                                                          \
    {                                                                          \
      const int ab = ((T) & 3) * 8192;                                         \
      half8 bf[4], af[4];                                                      \
      _Pragma("unroll") for (int nj = 0; nj < 4; ++nj)                         \
          bf[nj] = *(const half8*)(BsB + ab + bBase + nj * 512);               \
      _Pragma("unroll") for (int mi = 0; mi < 4; ++mi)                         \
          af[mi] = *(const half8*)(AsB + ab + aBase + mi * 512);               \
      __builtin_amdgcn_s_setprio(1);                                           \
      _Pragma("unroll") for (int mi = 0; mi < 4; ++mi)                         \
          _Pragma("unroll") for (int nj = 0; nj < 4; ++nj)                     \
          acc[mi][nj] = __builtin_amdgcn_mfma_f32_16x16x32_f16(                \
              af[mi], bf[nj], acc[mi][nj], 0, 0, 0);                           \
      __builtin_amdgcn_s_setprio(0);                                           \
      if (tt3 < NTILES) {                                                      \
        const int bo = (tt3 & 3) * 8192;                                       \
        const int kk = tt3 * 32;                                               \
        gload_lds16(bSrc0 + kk, BsB + bo + dst0);                              \
        gload_lds16(bSrc1 + kk, BsB + bo + dst1);                              \
      }                                                                        \
      _Pragma("unroll") for (int mi = 0; mi < 4; ++mi)                         \
          af[mi] = *(const half8*)(AsB + ab + aBase + (mi + 4) * 512);         \
      __builtin_amdgcn_s_setprio(1);                                           \
      _Pragma("unroll") for (int mi = 0; mi < 4; ++mi)                         \
          _Pragma("unroll") for (int nj = 0; nj < 4; ++nj)                     \
          acc[mi + 4][nj] = __builtin_amdgcn_mfma_f32_16x16x32_f16(            \
              af[mi], bf[nj], acc[mi + 4][nj], 0, 0, 0);                       \
      __builtin_amdgcn_s_setprio(0);                                           \
    }                                                                          \
  } while (0)

__global__ __launch_bounds__(512, 2) void gemm_f16(
    const _Float16* __restrict__ A, const _Float16* __restrict__ Bt,
    const float* __restrict__ latent_bias, float* __restrict__ C) {
  extern __shared__ _Float16 ldsbuf[];
  _Float16* AsB = ldsbuf;            // 4 bufs x 8192 halves (256x32)
  _Float16* BsB = ldsbuf + 4 * 8192;

  const int tid = threadIdx.x;
  const int lane = tid & 63, wave = tid >> 6;
  const int wr = wave >> 2, wc = wave & 3;

  int bid = blockIdx.x;
  int swz = (bid & 7) * (1024 >> 3) + (bid >> 3);
  const int bmBase = (swz >> 4) * 256;
  const int bnBase = (swz & 15) * 256;

  const int i0 = tid, i1 = 512 + tid;
  const int s0 = i0 ^ ((i0 >> 3) & 3), s1 = i1 ^ ((i1 >> 3) & 3);
  const _Float16* aSrc0 = A + (size_t)(bmBase + (s0 >> 2)) * D_DIM + (s0 & 3) * 8;
  const _Float16* aSrc1 = A + (size_t)(bmBase + (s1 >> 2)) * D_DIM + (s1 & 3) * 8;
  const _Float16* bSrc0 = Bt + (size_t)(bnBase + (s0 >> 2)) * D_DIM + (s0 & 3) * 8;
  const _Float16* bSrc1 = Bt + (size_t)(bnBase + (s1 >> 2)) * D_DIM + (s1 & 3) * 8;
  const int dst0 = i0 * 8, dst1 = i1 * 8;

  const int fr = lane & 15, c4 = lane >> 4;
  const int swzc = (c4 ^ ((fr >> 1) & 3)) * 8;
  const int aBase = (wr * 128 + fr) * 32 + swzc;
  const int bBase = (wc * 64 + fr) * 32 + swzc;

  f32x4 acc[8][4];
  #pragma unroll
  for (int i = 0; i < 8; ++i)
    #pragma unroll
    for (int j = 0; j < 4; ++j) acc[i][j] = f32x4{0.f, 0.f, 0.f, 0.f};

  #pragma unroll
  for (int tt = 0; tt < 3; ++tt) {
    const int bo = tt * 8192, kk = tt * 32;
    gload_lds16(aSrc0 + kk, AsB + bo + dst0);
    gload_lds16(aSrc1 + kk, AsB + bo + dst1);
    gload_lds16(bSrc0 + kk, BsB + bo + dst0);
    gload_lds16(bSrc1 + kk, BsB + bo + dst1);
  }

  for (int t = 0; t < NTILES - 2; ++t) TILE_BODY(t, "vmcnt(8)");
  TILE_BODY(NTILES - 2, "vmcnt(4)");
  TILE_BODY(NTILES - 1, "vmcnt(0)");

  const int crow0 = bmBase + wr * 128 + c4 * 4;
  const int ccol0 = bnBase + wc * 64 + fr;
  #pragma unroll
  for (int mi = 0; mi < 8; ++mi)
    #pragma unroll
    for (int nj = 0; nj < 4; ++nj) {
      int col = ccol0 + nj * 16;
      float lb = latent_bias[col];
      #pragma unroll
      for (int r = 0; r < 4; ++r)
        C[(size_t)(crow0 + mi * 16 + r) * D_DIM + col] = acc[mi][nj][r] + lb;
    }
}

// ------------------- fused top-k classify + fp64 rescue --------------------
// Histogram: 8192 bins of width 0.125 over [-512,512). Suffix scan finds
// bstar with count(>= edge) >= 64 -> T64_approx in [Tlo, Thi), width 0.125.
// Members: v > Thi+MARGIN (provably in exact top-64, provably < 64).
// Zone: [Tlo-MARGIN, Thi+MARGIN]. If |zone| == need: emit directly.
// Else: fp64 dots for zone candidates (wave-per-candidate), exact ranking
// with index tie-break. MARGIN=0.1875 is ~6 sigma of the fp16-GEMM error
// (0.026 rms) after T64 order-stat shift -- expected failures ~1e-8.

__global__ __launch_bounds__(256) void topk_full(
    const float* __restrict__ acts, const float* __restrict__ x,
    const float* __restrict__ WT, const float* __restrict__ pre_bias,
    const float* __restrict__ latent_bias, float* __restrict__ vals,
    int* __restrict__ idxs) {
  const int row = blockIdx.x;
  const int tid = threadIdx.x;
  const int lane = tid & 63, wave = tid >> 6;
  __shared__ int hist[8192];
  __shared__ int sred[8];
  __shared__ int ambL[128];
  __shared__ double exv[128];
  const float* arow = acts + (size_t)row * D_DIM;
  float fv[16];
  #pragma unroll
  for (int i = 0; i < 4; ++i) {
    float4 a = *(const float4*)(arow + i * 1024 + tid * 4);
    fv[4 * i + 0] = a.x; fv[4 * i + 1] = a.y;
    fv[4 * i + 2] = a.z; fv[4 * i + 3] = a.w;
  }
  #pragma unroll
  for (int i = 0; i < 32; ++i) hist[tid * 32 + i] = 0;
  __syncthreads();
  #pragma unroll
  for (int e = 0; e < 16; ++e) {
    int b = (int)((fv[e] + 512.0f) * 8.0f);
    b = b < 0 ? 0 : (b > 8191 ? 8191 : b);
    atomicAdd(&hist[b], 1);
  }
  __syncthreads();
  // local suffix over this thread's 32 contiguous bins
  int loc[32];
  int s = 0;
  #pragma unroll
  for (int i = 31; i >= 0; --i) { s += hist[tid * 32 + i]; loc[i] = s; }
  int xw = s;
  #pragma unroll
  for (int off = 1; off < 64; off <<= 1) {
    int y = __shfl_down(xw, off);
    if (lane + off < 64) xw += y;
  }
  if (lane == 0) sred[wave] = xw;  // wave total
  __syncthreads();
  int after = 0;
  for (int w = wave + 1; w < 4; ++w) after += sred[w];
  const int sufAfter = (xw - s) + after;
  int cand = -1;
  #pragma unroll
  for (int i = 0; i < 32; ++i)
    if (loc[i] + sufAfter >= TOPK) cand = tid * 32 + i;
  #pragma unroll
  for (int off = 32; off; off >>= 1) {
    int y = __shfl_down(cand, off);
    cand = y > cand ? y : cand;
  }
  if (lane == 0) sred[4 + wave] = cand;
  __syncthreads();
  int b0 = sred[4] > sred[5] ? sred[4] : sred[5];
  int b1 = sred[6] > sred[7] ? sred[6] : sred[7];
  const int bstar = b0 > b1 ? b0 : b1;  // exists: suffix(0) = 4096 >= 64
  const float Tlo = (bstar == 0) ? -1e30f : (bstar * 0.125f - 512.0f);
  const float Thi = (bstar >= 8191) ? 1e30f : ((bstar + 1) * 0.125f - 512.0f);
  const float vhi = Thi + MARGIN;
  const float vlo = Tlo - MARGIN;
  int mC = 0, aC = 0;
  #pragma unroll
  for (int i = 0; i < 16; ++i) {
    float v = fv[i];
    if (v > vhi) ++mC;
    else if (v >= vlo) ++aC;
  }
  int xs = mC | (aC << 16);
  #pragma unroll
  for (int off = 1; off < 64; off <<= 1) {
    int y = __shfl_up(xs, off);
    if (lane >= off) xs += y;
  }
  if (lane == 63) sred[wave] = xs;
  __syncthreads();
  int base = 0;
  for (int w = 0; w < 4; ++w)
    if (w < wave) base += sred[w];
  int tot = sred[0] + sred[1] + sred[2] + sred[3];
  int incl = base + xs;
  int mp = (incl & 0xffff) - mC;
  int ap = (incl >> 16) - aC;
  int mTot = tot & 0xffff, aTot = tot >> 16;
  const int need = TOPK - mTot;           // >= 1 (mTot <= 63 provably)
  const bool fast = (aTot == need);       // zone exactly fills the remainder
  #pragma unroll
  for (int e = 0; e < 16; ++e) {
    float v = fv[e];
    int d = (e >> 2) * 1024 + tid * 4 + (e & 3);
    if (v > vhi) {
      vals[(size_t)row * TOPK + mp] = fmaxf(v, 0.0f);
      idxs[(size_t)row * TOPK + mp] = d;
      ++mp;
    } else if (v >= vlo) {
      if (fast) {
        vals[(size_t)row * TOPK + mTot + ap] = fmaxf(v, 0.0f);
        idxs[(size_t)row * TOPK + mTot + ap] = d;
      } else if (ap < 128) {
        ambL[ap] = d;
      }
      ++ap;
    }
  }
  if (fast) return;

  // ---- fp64 rescue of the ambiguous zone (uniform path) ----
  __syncthreads();  // ambL visible to all waves
  const int sN = aTot > 128 ? 128 : aTot;
  const float* xr = x + (size_t)row * D_DIM;
  for (int c = wave; c < sN; c += 4) {
    int d = ambL[c];
    const float* wrow = WT + (size_t)d * D_DIM;
    double acc = 0.0;
    #pragma unroll 4
    for (int t = 0; t < 16; ++t) {
      int k0 = t * 256 + lane * 4;
      float4 xv = *(const float4*)(xr + k0);
      float4 pv = *(const float4*)(pre_bias + k0);
      float4 wv = *(const float4*)(wrow + k0);
      acc = fma((double)xv.x - (double)pv.x, (double)wv.x, acc);
      acc = fma((double)xv.y - (double)pv.y, (double)wv.y, acc);
      acc = fma((double)xv.z - (double)pv.z, (double)wv.z, acc);
      acc = fma((double)xv.w - (double)pv.w, (double)wv.w, acc);
    }
    #pragma unroll
    for (int off = 32; off; off >>= 1) acc += __shfl_down(acc, off);
    if (lane == 0) exv[c] = acc + (double)latent_bias[d];
  }
  __syncthreads();
  if (tid == 0) {
    for (int t = 0; t < need; ++t) {
      double best = -1.0e300; int besti = 1 << 30; int bestc = -1;
      for (int c = 0; c < sN; ++c) {
        double v = exv[c];
        int d = ambL[c];
        if (v > best || (v == best && d < besti)) {
          best = v; besti = d; bestc = c;
        }
      }
      vals[(size_t)row * TOPK + mTot + t] = fmaxf((float)best, 0.0f);
      idxs[(size_t)row * TOPK + mTot + t] = besti;
      exv[bestc] = -1.0e300;
    }
  }
}

// ----------------------------- reconstruct ---------------------------------

__global__ __launch_bounds__(256) void reconstruct(
    const unsigned short* __restrict__ Wd, const float* __restrict__ vals,
    const int* __restrict__ idxs, const float* __restrict__ pre_bias,
    float* __restrict__ out) {
  const int bid = blockIdx.x;
  const int cb = bid & 7, rowblk = bid >> 3;
  const int tid = threadIdx.x, lane = tid & 63, wave = tid >> 6;
  const int row = rowblk * 4 + wave;
  const int col0 = cb * 512 + lane * 8;
  __shared__ float sval[256];
  __shared__ int sidx[256];
  sval[tid] = vals[(size_t)(rowblk * 4 + (tid >> 6)) * TOPK + (tid & 63)];
  sidx[tid] = idxs[(size_t)(rowblk * 4 + (tid >> 6)) * TOPK + (tid & 63)];
  __syncthreads();
  float acc[8];
  float4 p0 = *(const float4*)(pre_bias + col0);
  float4 p1 = *(const float4*)(pre_bias + col0 + 4);
  acc[0] = p0.x; acc[1] = p0.y; acc[2] = p0.z; acc[3] = p0.w;
  acc[4] = p1.x; acc[5] = p1.y; acc[6] = p1.z; acc[7] = p1.w;
  #pragma unroll 4
  for (int k = 0; k < TOPK; ++k) {
    float v = sval[wave * 64 + k];
    int d = sidx[wave * 64 + k];
    ushort8 w = *(const ushort8*)(Wd + (size_t)d * D_DIM + col0);
    #pragma unroll
    for (int j = 0; j < 8; ++j)
      acc[j] = fmaf(v, __uint_as_float(((unsigned)w[j]) << 16), acc[j]);
  }
  float4 o0 = {acc[0], acc[1], acc[2], acc[3]};
  float4 o1 = {acc[4], acc[5], acc[6], acc[7]};
  *(float4*)(out + (size_t)row * D_DIM + col0) = o0;
  *(float4*)(out + (size_t)row * D_DIM + col0 + 4) = o1;
}

// ------------------------------- launcher ----------------------------------

extern "C" void kernel_launch(void* const* d_in, const int* in_sizes, int n_in,
                              void* d_out, int out_size, void* d_ws,
                              size_t ws_size, hipStream_t stream) {
  const float* x           = (const float*)d_in[0];
  // d_in[1] = ema_frequency_counter (unused by reference)
  const float* W_enc       = (const float*)d_in[2];
  const float* W_dec       = (const float*)d_in[3];
  const float* pre_bias    = (const float*)d_in[4];
  const float* latent_bias = (const float*)d_in[5];
  float* out = (float*)d_out;  // doubles as acts buffer, overwritten last
  char* ws = (char*)d_ws;
  size_t off = 0;
  auto alloc = [&](size_t bytes) {
    size_t o = off;
    off = (off + bytes + 255) & ~(size_t)255;
    return o;
  };
  _Float16* Xh        = (_Float16*)(ws + alloc((size_t)B_ROWS * D_DIM * 2));
  _Float16* WhT       = (_Float16*)(ws + alloc((size_t)D_DIM * D_DIM * 2));
  float* WT           = (float*)(ws + alloc((size_t)D_DIM * D_DIM * 4));
  unsigned short* Wd  = (unsigned short*)(ws + alloc((size_t)D_DIM * D_DIM * 2));
  float* vals         = (float*)(ws + alloc((size_t)B_ROWS * TOPK * 4));
  int* idxs           = (int*)(ws + alloc((size_t)B_ROWS * TOPK * 4));
  (void)ws_size; (void)in_sizes; (void)n_in; (void)out_size;

  // allow 128KB dynamic LDS for the GEMM (cheap, deterministic, idempotent)
  (void)hipFuncSetAttribute((const void*)gemm_f16,
                            hipFuncAttributeMaxDynamicSharedMemorySize,
                            131072);

  conv_x<<<(B_ROWS * D_DIM / 8) / 256, 256, 0, stream>>>(x, pre_bias, Xh);
  transp_w<<<dim3(D_DIM / 64, D_DIM / 64), 256, 0, stream>>>(W_enc, WhT, WT);
  conv_wd<<<((size_t)D_DIM * D_DIM / 8) / 256, 256, 0, stream>>>(W_dec, Wd);
  gemm_f16<<<(B_ROWS / 256) * (D_DIM / 256), 512, 131072, stream>>>(
      Xh, WhT, latent_bias, out);
  topk_full<<<B_ROWS, 256, 0, stream>>>(out, x, WT, pre_bias, latent_bias,
                                        vals, idxs);
  reconstruct<<<(B_ROWS / 4) * 8, 256, 0, stream>>>(Wd, vals, idxs, pre_bias,
                                                    out);
}

// Round 10
// 1154.799 us; speedup vs baseline: 1.0124x; 1.0124x over previous
//
#include <hip/hip_runtime.h>
#include <hip/hip_bf16.h>
#include <stdint.h>

// ---------------------------------------------------------------------------
// TopKAutoEncoder forward, MI355X.
// acts = (x - pre_bias) @ W_enc + latent_bias   [16384 x 4096]
// top-64/row (exact selection vs ref), relu, @ W_dec + pre_bias.
//
// R10 GEMM: 256x256 tile, 1024 threads / 16 waves (4M x 4N, 64x64 out each,
// 4 waves/SIMD for TLP), BK=32, 4-deep LDS pipeline (128KB), counted
// vmcnt(4/2/0), chunk-XOR swizzle f(r)=(r>>1)&3 (0 bank conflicts), XCD
// block swizzle, setprio. Addressing identical to verified R3.
// topk: R8 form -- histogram classify (4096 x 0.25 bins, MARGIN 0.25) +
// separate fp64 rescue of the ambiguous zone (fast-path in classify).
// bf16 sparse reconstruct with XCD-L2-resident W_dec slabs.
// ---------------------------------------------------------------------------

typedef _Float16 half8 __attribute__((ext_vector_type(8)));
typedef float f32x4 __attribute__((ext_vector_type(4)));
typedef unsigned short ushort8 __attribute__((ext_vector_type(8)));

#define B_ROWS 16384
#define D_DIM  4096
#define TOPK   64
#define MARGIN 0.25f
#define NTILES (D_DIM / 32)

__device__ __forceinline__ void gload_lds16(const void* g, void* l) {
  __builtin_amdgcn_global_load_lds(
      (const __attribute__((address_space(1))) unsigned int*)g,
      (__attribute__((address_space(3))) unsigned int*)l, 16, 0, 0);
}

__device__ __forceinline__ unsigned short f2bf(float f) {
  unsigned u = __float_as_uint(f);
  unsigned r = (u + 0x7fffu + ((u >> 16) & 1u)) >> 16;
  return (unsigned short)r;
}

// --------------------------- conversion kernels ----------------------------

__global__ __launch_bounds__(256) void conv_x(
    const float* __restrict__ x, const float* __restrict__ pre_bias,
    _Float16* __restrict__ Xh) {
  size_t g = ((size_t)blockIdx.x * 256 + threadIdx.x) * 8;
  int col = (int)(g & (D_DIM - 1));
  float4 a = *(const float4*)(x + g);
  float4 b = *(const float4*)(x + g + 4);
  float4 p = *(const float4*)(pre_bias + col);
  float4 q = *(const float4*)(pre_bias + col + 4);
  half8 h;
  h[0] = (_Float16)(a.x - p.x); h[1] = (_Float16)(a.y - p.y);
  h[2] = (_Float16)(a.z - p.z); h[3] = (_Float16)(a.w - p.w);
  h[4] = (_Float16)(b.x - q.x); h[5] = (_Float16)(b.y - q.y);
  h[6] = (_Float16)(b.z - q.z); h[7] = (_Float16)(b.w - q.w);
  *(half8*)(Xh + g) = h;
}

// W_enc [K][N] fp32 -> WhT [N][K] fp16  AND WT [N][K] fp32 (for fp64 rescue)
__global__ __launch_bounds__(256) void transp_w(
    const float* __restrict__ W, _Float16* __restrict__ WhT,
    float* __restrict__ WT) {
  __shared__ float tile[64][65];
  int bx = blockIdx.x, by = blockIdx.y;
  int tx = threadIdx.x & 63, ty4 = threadIdx.x >> 6;
  #pragma unroll 4
  for (int i = 0; i < 16; ++i) {
    int r = ty4 * 16 + i;
    tile[r][tx] = W[(size_t)(by * 64 + r) * D_DIM + bx * 64 + tx];
  }
  __syncthreads();
  #pragma unroll 4
  for (int i = 0; i < 16; ++i) {
    int r = ty4 * 16 + i;
    float v = tile[tx][r];
    size_t o = (size_t)(bx * 64 + r) * D_DIM + by * 64 + tx;
    WT[o] = v;
    WhT[o] = (_Float16)v;
  }
}

__global__ __launch_bounds__(256) void conv_wd(
    const float* __restrict__ W, unsigned short* __restrict__ o) {
  size_t g = ((size_t)blockIdx.x * 256 + threadIdx.x) * 8;
  float4 a = *(const float4*)(W + g);
  float4 b = *(const float4*)(W + g + 4);
  ushort8 v;
  v[0] = f2bf(a.x); v[1] = f2bf(a.y); v[2] = f2bf(a.z); v[3] = f2bf(a.w);
  v[4] = f2bf(b.x); v[5] = f2bf(b.y); v[6] = f2bf(b.z); v[7] = f2bf(b.w);
  *(ushort8*)(o + g) = v;
}

// ------------------------------- fp16 GEMM ---------------------------------
// 16 waves (4M x 4N), per-wave 64x64 out, acc[4][4] f32x4 = 64 regs.
// Per-thread staging: 1 A-slot + 1 B-slot per tile (2 loads). 4-buf cycle,
// stage t+3 in body t. Per-thread FIFO ledger: at top of body t outstanding
// <= 6 (stages t,t+1,t+2); vmcnt(4) completes stage(t); barrier makes it
// block-visible (vmcnt is per-wave -- R4 lesson). Tails: vmcnt(2), vmcnt(0).
// Chunk-XOR swizzle identical to verified R3: phys slot i holds logical
// chunk i ^ ((i>>3)&3); read logical chunk c of row r at phys c^((r>>1)&3)
// -> all 8 bank groups hit exactly 2x per 16-lane quarter (2-way = free).

#define TILE_BODY(T, VMSTR)                                                    \
  do {                                                                         \
    asm volatile("s_waitcnt " VMSTR ::: "memory");                             \
    __builtin_amdgcn_s_barrier();                                              \
    asm volatile("" ::: "memory");                                             \
    const int tt3 = (T) + 3;                                                   \
    if (tt3 < NTILES) {                                                        \
      const int bo = (tt3 & 3) * 8192;                                         \
      const int kk = tt3 * 32;                                                 \
      gload_lds16(aSrc + kk, AsB + bo + dstL);                                 \
      gload_lds16(bSrc + kk, BsB + bo + dstL);                                 \
    }                                                                          \
    {                                                                          \
      const int ab = ((T) & 3) * 8192;                                         \
      half8 bf[4], af[4];                                                      \
      _Pragma("unroll") for (int nj = 0; nj < 4; ++nj)                         \
          bf[nj] = *(const half8*)(BsB + ab + bBase + nj * 512);               \
      _Pragma("unroll") for (int mi = 0; mi < 4; ++mi)                         \
          af[mi] = *(const half8*)(AsB + ab + aBase + mi * 512);               \
      __builtin_amdgcn_s_setprio(1);                                           \
      _Pragma("unroll") for (int mi = 0; mi < 4; ++mi)                         \
          _Pragma("unroll") for (int nj = 0; nj < 4; ++nj)                     \
          acc[mi][nj] = __builtin_amdgcn_mfma_f32_16x16x32_f16(                \
              af[mi], bf[nj], acc[mi][nj], 0, 0, 0);                           \
      __builtin_amdgcn_s_setprio(0);                                           \
    }                                                                          \
  } while (0)

__global__ __launch_bounds__(1024, 4) void gemm_f16(
    const _Float16* __restrict__ A, const _Float16* __restrict__ Bt,
    const float* __restrict__ latent_bias, float* __restrict__ C) {
  extern __shared__ _Float16 ldsbuf[];
  _Float16* AsB = ldsbuf;            // 4 bufs x 8192 halves (256x32)
  _Float16* BsB = ldsbuf + 4 * 8192;

  const int tid = threadIdx.x;
  const int lane = tid & 63, wave = tid >> 6;   // wave 0..15
  const int wm = wave >> 2, wn = wave & 3;      // 4M x 4N

  // XCD-aware swizzle; grid = 64*16 = 1024, divisible by 8 -> bijective.
  int bid = blockIdx.x;
  int swz = (bid & 7) * (1024 >> 3) + (bid >> 3);
  const int bmBase = (swz >> 4) * 256;
  const int bnBase = (swz & 15) * 256;

  // staging: 1024 slots per operand per buf; thread tid owns slot tid of
  // both A and B. phys slot i holds logical chunk s = i ^ ((i>>3)&3).
  const int s = tid ^ ((tid >> 3) & 3);
  const _Float16* aSrc = A + (size_t)(bmBase + (s >> 2)) * D_DIM + (s & 3) * 8;
  const _Float16* bSrc = Bt + (size_t)(bnBase + (s >> 2)) * D_DIM + (s & 3) * 8;
  const int dstL = tid * 8;

  // fragment reads: logical chunk c4 of row r at phys c4 ^ ((r>>1)&3)
  const int fr = lane & 15, c4 = lane >> 4;
  const int swzc = (c4 ^ ((fr >> 1) & 3)) * 8;
  const int aBase = (wm * 64 + fr) * 32 + swzc;
  const int bBase = (wn * 64 + fr) * 32 + swzc;

  f32x4 acc[4][4];
  #pragma unroll
  for (int i = 0; i < 4; ++i)
    #pragma unroll
    for (int j = 0; j < 4; ++j) acc[i][j] = f32x4{0.f, 0.f, 0.f, 0.f};

  // prologue: stage tiles 0,1,2 (6 loads/thread); wait own tile-0 loads;
  // barrier for cross-wave visibility; loop.
  #pragma unroll
  for (int tt = 0; tt < 3; ++tt) {
    const int bo = tt * 8192, kk = tt * 32;
    gload_lds16(aSrc + kk, AsB + bo + dstL);
    gload_lds16(bSrc + kk, BsB + bo + dstL);
  }

  for (int t = 0; t < NTILES - 2; ++t) TILE_BODY(t, "vmcnt(4)");
  TILE_BODY(NTILES - 2, "vmcnt(2)");
  TILE_BODY(NTILES - 1, "vmcnt(0)");

  // epilogue (verified C/D mapping: col=lane&15 within 16x16, row quad c4)
  const int crow0 = bmBase + wm * 64 + c4 * 4;
  const int ccol0 = bnBase + wn * 64 + fr;
  #pragma unroll
  for (int mi = 0; mi < 4; ++mi)
    #pragma unroll
    for (int nj = 0; nj < 4; ++nj) {
      int col = ccol0 + nj * 16;
      float lb = latent_bias[col];
      #pragma unroll
      for (int r = 0; r < 4; ++r)
        C[(size_t)(crow0 + mi * 16 + r) * D_DIM + col] = acc[mi][nj][r] + lb;
    }
}

// --------------------------- top-k classify (R8 form) ----------------------
// Single pass: 4096 bins of width 0.25 over [-512,512). Suffix-count scan
// finds bstar = largest bin with count(>= edge) >= 64 -> T64_approx in
// [Tlo, Thi), width 0.25. Members: v > Thi+MARGIN (provably in exact
// top-64, provably < 64). Zone: [Tlo-MARGIN, Thi+MARGIN]. Fast path:
// |zone| == need -> emit directly, no rescue.

__global__ __launch_bounds__(256) void topk_classify(
    const float* __restrict__ acts, float* __restrict__ vals,
    int* __restrict__ idxs, int* __restrict__ ambIdx,
    int* __restrict__ rowMeta) {
  const int row = blockIdx.x;
  const int tid = threadIdx.x;
  const int lane = tid & 63, wave = tid >> 6;
  __shared__ int hist[4096];
  __shared__ int sred[8];
  const float* arow = acts + (size_t)row * D_DIM;
  float fv[16];
  #pragma unroll
  for (int i = 0; i < 4; ++i) {
    float4 a = *(const float4*)(arow + i * 1024 + tid * 4);
    fv[4 * i + 0] = a.x; fv[4 * i + 1] = a.y;
    fv[4 * i + 2] = a.z; fv[4 * i + 3] = a.w;
  }
  #pragma unroll
  for (int i = 0; i < 16; ++i) hist[tid * 16 + i] = 0;
  __syncthreads();
  #pragma unroll
  for (int e = 0; e < 16; ++e) {
    int b = (int)((fv[e] + 512.0f) * 4.0f);
    b = b < 0 ? 0 : (b > 4095 ? 4095 : b);
    atomicAdd(&hist[b], 1);
  }
  __syncthreads();
  int loc[16];
  int s = 0;
  #pragma unroll
  for (int i = 15; i >= 0; --i) { s += hist[tid * 16 + i]; loc[i] = s; }
  int x = s;
  #pragma unroll
  for (int off = 1; off < 64; off <<= 1) {
    int y = __shfl_down(x, off);
    if (lane + off < 64) x += y;
  }
  if (lane == 0) sred[wave] = x;
  __syncthreads();
  int after = 0;
  for (int w = wave + 1; w < 4; ++w) after += sred[w];
  const int sufAfter = (x - s) + after;
  int cand = -1;
  #pragma unroll
  for (int i = 0; i < 16; ++i)
    if (loc[i] + sufAfter >= TOPK) cand = tid * 16 + i;
  #pragma unroll
  for (int off = 32; off; off >>= 1) {
    int y = __shfl_down(cand, off);
    cand = y > cand ? y : cand;
  }
  if (lane == 0) sred[4 + wave] = cand;
  __syncthreads();
  int b0 = sred[4] > sred[5] ? sred[4] : sred[5];
  int b1 = sred[6] > sred[7] ? sred[6] : sred[7];
  const int bstar = b0 > b1 ? b0 : b1;
  const float Tlo = (bstar == 0) ? -1e30f : (bstar * 0.25f - 512.0f);
  const float Thi = (bstar >= 4095) ? 1e30f : ((bstar + 1) * 0.25f - 512.0f);
  const float vhi = Thi + MARGIN;
  const float vlo = Tlo - MARGIN;
  int mC = 0, aC = 0;
  #pragma unroll
  for (int i = 0; i < 16; ++i) {
    float v = fv[i];
    if (v > vhi) ++mC;
    else if (v >= vlo) ++aC;
  }
  int xs = mC | (aC << 16);
  #pragma unroll
  for (int off = 1; off < 64; off <<= 1) {
    int y = __shfl_up(xs, off);
    if (lane >= off) xs += y;
  }
  if (lane == 63) sred[wave] = xs;
  __syncthreads();
  int base = 0;
  for (int w = 0; w < 4; ++w)
    if (w < wave) base += sred[w];
  int tot = sred[0] + sred[1] + sred[2] + sred[3];
  int incl = base + xs;
  int mp = (incl & 0xffff) - mC;
  int ap = (incl >> 16) - aC;
  int mTot = tot & 0xffff, aTot = tot >> 16;
  const int need = TOPK - mTot;
  const bool fast = (aTot == need);
  #pragma unroll
  for (int e = 0; e < 16; ++e) {
    float v = fv[e];
    int d = (e >> 2) * 1024 + tid * 4 + (e & 3);
    if (v > vhi) {
      vals[(size_t)row * TOPK + mp] = fmaxf(v, 0.0f);
      idxs[(size_t)row * TOPK + mp] = d;
      ++mp;
    } else if (v >= vlo) {
      if (fast) {
        vals[(size_t)row * TOPK + mTot + ap] = fmaxf(v, 0.0f);
        idxs[(size_t)row * TOPK + mTot + ap] = d;
      } else if (ap < 128) {
        ambIdx[(size_t)row * 128 + ap] = d;
      }
      ++ap;
    }
  }
  if (tid == 0) {
    rowMeta[row * 2 + 0] = mTot;
    rowMeta[row * 2 + 1] = (fast || need <= 0) ? 0 : ((aTot > 128) ? 128 : aTot);
  }
}

// ------------------------------ fp64 rescue --------------------------------

__global__ __launch_bounds__(256) void rescue(
    const float* __restrict__ x, const float* __restrict__ WT,
    const float* __restrict__ pre_bias, const float* __restrict__ latent_bias,
    const float* __restrict__ acts, const int* __restrict__ ambIdx,
    const int* __restrict__ rowMeta, float* __restrict__ vals,
    int* __restrict__ idxs) {
  const int row = blockIdx.x;
  const int m = rowMeta[row * 2 + 0];
  const int s = rowMeta[row * 2 + 1];
  const int need = TOPK - m;
  const int tid = threadIdx.x;
  if (need <= 0 || s <= 0) return;
  if (s == need) {  // residual fast path (normally resolved in classify)
    if (tid < s) {
      int d = ambIdx[(size_t)row * 128 + tid];
      float v = acts[(size_t)row * D_DIM + d];
      vals[(size_t)row * TOPK + m + tid] = fmaxf(v, 0.0f);
      idxs[(size_t)row * TOPK + m + tid] = d;
    }
    return;
  }
  __shared__ double exv[128];
  const int lane = tid & 63, wave = tid >> 6;
  const float* xr = x + (size_t)row * D_DIM;
  for (int c = wave; c < s; c += 4) {
    int d = ambIdx[(size_t)row * 128 + c];
    const float* wrow = WT + (size_t)d * D_DIM;
    double acc = 0.0;
    #pragma unroll 4
    for (int t = 0; t < 16; ++t) {
      int k0 = t * 256 + lane * 4;
      float4 xv = *(const float4*)(xr + k0);
      float4 pv = *(const float4*)(pre_bias + k0);
      float4 wv = *(const float4*)(wrow + k0);
      acc = fma((double)xv.x - (double)pv.x, (double)wv.x, acc);
      acc = fma((double)xv.y - (double)pv.y, (double)wv.y, acc);
      acc = fma((double)xv.z - (double)pv.z, (double)wv.z, acc);
      acc = fma((double)xv.w - (double)pv.w, (double)wv.w, acc);
    }
    #pragma unroll
    for (int off = 32; off; off >>= 1) acc += __shfl_down(acc, off);
    if (lane == 0) exv[c] = acc + (double)latent_bias[d];
  }
  __syncthreads();
  if (tid == 0) {
    for (int t = 0; t < need; ++t) {
      double best = -1.0e300; int besti = 1 << 30; int bestc = -1;
      for (int c = 0; c < s; ++c) {
        double v = exv[c];
        int d = ambIdx[(size_t)row * 128 + c];
        if (v > best || (v == best && d < besti)) {
          best = v; besti = d; bestc = c;
        }
      }
      vals[(size_t)row * TOPK + m + t] = fmaxf((float)best, 0.0f);
      idxs[(size_t)row * TOPK + m + t] = besti;
      exv[bestc] = -1.0e300;
    }
  }
}

// ----------------------------- reconstruct ---------------------------------

__global__ __launch_bounds__(256) void reconstruct(
    const unsigned short* __restrict__ Wd, const float* __restrict__ vals,
    const int* __restrict__ idxs, const float* __restrict__ pre_bias,
    float* __restrict__ out) {
  const int bid = blockIdx.x;
  const int cb = bid & 7, rowblk = bid >> 3;
  const int tid = threadIdx.x, lane = tid & 63, wave = tid >> 6;
  const int row = rowblk * 4 + wave;
  const int col0 = cb * 512 + lane * 8;
  __shared__ float sval[256];
  __shared__ int sidx[256];
  sval[tid] = vals[(size_t)(rowblk * 4 + (tid >> 6)) * TOPK + (tid & 63)];
  sidx[tid] = idxs[(size_t)(rowblk * 4 + (tid >> 6)) * TOPK + (tid & 63)];
  __syncthreads();
  float acc[8];
  float4 p0 = *(const float4*)(pre_bias + col0);
  float4 p1 = *(const float4*)(pre_bias + col0 + 4);
  acc[0] = p0.x; acc[1] = p0.y; acc[2] = p0.z; acc[3] = p0.w;
  acc[4] = p1.x; acc[5] = p1.y; acc[6] = p1.z; acc[7] = p1.w;
  #pragma unroll 4
  for (int k = 0; k < TOPK; ++k) {
    float v = sval[wave * 64 + k];
    int d = sidx[wave * 64 + k];
    ushort8 w = *(const ushort8*)(Wd + (size_t)d * D_DIM + col0);
    #pragma unroll
    for (int j = 0; j < 8; ++j)
      acc[j] = fmaf(v, __uint_as_float(((unsigned)w[j]) << 16), acc[j]);
  }
  float4 o0 = {acc[0], acc[1], acc[2], acc[3]};
  float4 o1 = {acc[4], acc[5], acc[6], acc[7]};
  *(float4*)(out + (size_t)row * D_DIM + col0) = o0;
  *(float4*)(out + (size_t)row * D_DIM + col0 + 4) = o1;
}

// ------------------------------- launcher ----------------------------------

extern "C" void kernel_launch(void* const* d_in, const int* in_sizes, int n_in,
                              void* d_out, int out_size, void* d_ws,
                              size_t ws_size, hipStream_t stream) {
  const float* x           = (const float*)d_in[0];
  // d_in[1] = ema_frequency_counter (unused by reference)
  const float* W_enc       = (const float*)d_in[2];
  const float* W_dec       = (const float*)d_in[3];
  const float* pre_bias    = (const float*)d_in[4];
  const float* latent_bias = (const float*)d_in[5];
  float* out = (float*)d_out;  // doubles as acts buffer, overwritten last
  char* ws = (char*)d_ws;
  size_t off = 0;
  auto alloc = [&](size_t bytes) {
    size_t o = off;
    off = (off + bytes + 255) & ~(size_t)255;
    return o;
  };
  _Float16* Xh        = (_Float16*)(ws + alloc((size_t)B_ROWS * D_DIM * 2));
  _Float16* WhT       = (_Float16*)(ws + alloc((size_t)D_DIM * D_DIM * 2));
  float* WT           = (float*)(ws + alloc((size_t)D_DIM * D_DIM * 4));
  unsigned short* Wd  = (unsigned short*)(ws + alloc((size_t)D_DIM * D_DIM * 2));
  float* vals         = (float*)(ws + alloc((size_t)B_ROWS * TOPK * 4));
  int* idxs           = (int*)(ws + alloc((size_t)B_ROWS * TOPK * 4));
  int* ambIdx         = (int*)(ws + alloc((size_t)B_ROWS * 128 * 4));
  int* rowMeta        = (int*)(ws + alloc((size_t)B_ROWS * 2 * 4));
  (void)ws_size; (void)in_sizes; (void)n_in; (void)out_size;

  // allow 128KB dynamic LDS for the GEMM (cheap, deterministic, idempotent)
  (void)hipFuncSetAttribute((const void*)gemm_f16,
                            hipFuncAttributeMaxDynamicSharedMemorySize,
                            131072);

  conv_x<<<(B_ROWS * D_DIM / 8) / 256, 256, 0, stream>>>(x, pre_bias, Xh);
  transp_w<<<dim3(D_DIM / 64, D_DIM / 64), 256, 0, stream>>>(W_enc, WhT, WT);
  conv_wd<<<((size_t)D_DIM * D_DIM / 8) / 256, 256, 0, stream>>>(W_dec, Wd);
  gemm_f16<<<(B_ROWS / 256) * (D_DIM / 256), 1024, 131072, stream>>>(
      Xh, WhT, latent_bias, out);
  topk_classify<<<B_ROWS, 256, 0, stream>>>(out, vals, idxs, ambIdx, rowMeta);
  rescue<<<B_ROWS, 256, 0, stream>>>(x, WT, pre_bias, latent_bias, out,
                                     ambIdx, rowMeta, vals, idxs);
  reconstruct<<<(B_ROWS / 4) * 8, 256, 0, stream>>>(Wd, vals, idxs, pre_bias,
                                                    out);
}

// Round 11
// 1148.405 us; speedup vs baseline: 1.0180x; 1.0056x over previous
//
#include <hip/hip_runtime.h>
#include <hip/hip_bf16.h>
#include <stdint.h>

// ---------------------------------------------------------------------------
// TopKAutoEncoder forward, MI355X.
// acts = (x - pre_bias) @ W_enc + latent_bias   [16384 x 4096]
// top-64/row (exact selection vs ref), relu, @ W_dec + pre_bias.
//
// GEMM (R10, measured best): 256x256 tile, 1024 thr / 16 waves (4Mx4N,
// 64x64 out each, 4 waves/SIMD), BK=32, 4-deep LDS pipeline, counted
// vmcnt(4/2/0), chunk-XOR swizzle (0 bank conflicts), XCD swizzle, setprio.
// R11 topk_full: TWO-LEVEL histogram (256 coarse x 4.0 + 256 fine x
// 0.015625, 2KB LDS) -> T64 bracket width 0.0156; zone [Tlo-M, Thi+M],
// M=0.25; fp64 boundary rescue FUSED in-kernel (wave-per-candidate).
// bf16 sparse reconstruct with XCD-L2-resident W_dec slabs.
// ---------------------------------------------------------------------------

typedef _Float16 half8 __attribute__((ext_vector_type(8)));
typedef float f32x4 __attribute__((ext_vector_type(4)));
typedef unsigned short ushort8 __attribute__((ext_vector_type(8)));

#define B_ROWS 16384
#define D_DIM  4096
#define TOPK   64
#define MARGIN 0.25f
#define NTILES (D_DIM / 32)

__device__ __forceinline__ void gload_lds16(const void* g, void* l) {
  __builtin_amdgcn_global_load_lds(
      (const __attribute__((address_space(1))) unsigned int*)g,
      (__attribute__((address_space(3))) unsigned int*)l, 16, 0, 0);
}

__device__ __forceinline__ unsigned short f2bf(float f) {
  unsigned u = __float_as_uint(f);
  unsigned r = (u + 0x7fffu + ((u >> 16) & 1u)) >> 16;
  return (unsigned short)r;
}

// --------------------------- conversion kernels ----------------------------

__global__ __launch_bounds__(256) void conv_x(
    const float* __restrict__ x, const float* __restrict__ pre_bias,
    _Float16* __restrict__ Xh) {
  size_t g = ((size_t)blockIdx.x * 256 + threadIdx.x) * 8;
  int col = (int)(g & (D_DIM - 1));
  float4 a = *(const float4*)(x + g);
  float4 b = *(const float4*)(x + g + 4);
  float4 p = *(const float4*)(pre_bias + col);
  float4 q = *(const float4*)(pre_bias + col + 4);
  half8 h;
  h[0] = (_Float16)(a.x - p.x); h[1] = (_Float16)(a.y - p.y);
  h[2] = (_Float16)(a.z - p.z); h[3] = (_Float16)(a.w - p.w);
  h[4] = (_Float16)(b.x - q.x); h[5] = (_Float16)(b.y - q.y);
  h[6] = (_Float16)(b.z - q.z); h[7] = (_Float16)(b.w - q.w);
  *(half8*)(Xh + g) = h;
}

// W_enc [K][N] fp32 -> WhT [N][K] fp16  AND WT [N][K] fp32 (for fp64 rescue)
__global__ __launch_bounds__(256) void transp_w(
    const float* __restrict__ W, _Float16* __restrict__ WhT,
    float* __restrict__ WT) {
  __shared__ float tile[64][65];
  int bx = blockIdx.x, by = blockIdx.y;
  int tx = threadIdx.x & 63, ty4 = threadIdx.x >> 6;
  #pragma unroll 4
  for (int i = 0; i < 16; ++i) {
    int r = ty4 * 16 + i;
    tile[r][tx] = W[(size_t)(by * 64 + r) * D_DIM + bx * 64 + tx];
  }
  __syncthreads();
  #pragma unroll 4
  for (int i = 0; i < 16; ++i) {
    int r = ty4 * 16 + i;
    float v = tile[tx][r];
    size_t o = (size_t)(bx * 64 + r) * D_DIM + by * 64 + tx;
    WT[o] = v;
    WhT[o] = (_Float16)v;
  }
}

__global__ __launch_bounds__(256) void conv_wd(
    const float* __restrict__ W, unsigned short* __restrict__ o) {
  size_t g = ((size_t)blockIdx.x * 256 + threadIdx.x) * 8;
  float4 a = *(const float4*)(W + g);
  float4 b = *(const float4*)(W + g + 4);
  ushort8 v;
  v[0] = f2bf(a.x); v[1] = f2bf(a.y); v[2] = f2bf(a.z); v[3] = f2bf(a.w);
  v[4] = f2bf(b.x); v[5] = f2bf(b.y); v[6] = f2bf(b.z); v[7] = f2bf(b.w);
  *(ushort8*)(o + g) = v;
}

// ------------------------------- fp16 GEMM (R10 verbatim) ------------------

#define TILE_BODY(T, VMSTR)                                                    \
  do {                                                                         \
    asm volatile("s_waitcnt " VMSTR ::: "memory");                             \
    __builtin_amdgcn_s_barrier();                                              \
    asm volatile("" ::: "memory");                                             \
    const int tt3 = (T) + 3;                                                   \
    if (tt3 < NTILES) {                                                        \
      const int bo = (tt3 & 3) * 8192;                                         \
      const int kk = tt3 * 32;                                                 \
      gload_lds16(aSrc + kk, AsB + bo + dstL);                                 \
      gload_lds16(bSrc + kk, BsB + bo + dstL);                                 \
    }                                                                          \
    {                                                                          \
      const int ab = ((T) & 3) * 8192;                                         \
      half8 bf[4], af[4];                                                      \
      _Pragma("unroll") for (int nj = 0; nj < 4; ++nj)                         \
          bf[nj] = *(const half8*)(BsB + ab + bBase + nj * 512);               \
      _Pragma("unroll") for (int mi = 0; mi < 4; ++mi)                         \
          af[mi] = *(const half8*)(AsB + ab + aBase + mi * 512);               \
      __builtin_amdgcn_s_setprio(1);                                           \
      _Pragma("unroll") for (int mi = 0; mi < 4; ++mi)                         \
          _Pragma("unroll") for (int nj = 0; nj < 4; ++nj)                     \
          acc[mi][nj] = __builtin_amdgcn_mfma_f32_16x16x32_f16(                \
              af[mi], bf[nj], acc[mi][nj], 0, 0, 0);                           \
      __builtin_amdgcn_s_setprio(0);                                           \
    }                                                                          \
  } while (0)

__global__ __launch_bounds__(1024, 4) void gemm_f16(
    const _Float16* __restrict__ A, const _Float16* __restrict__ Bt,
    const float* __restrict__ latent_bias, float* __restrict__ C) {
  extern __shared__ _Float16 ldsbuf[];
  _Float16* AsB = ldsbuf;            // 4 bufs x 8192 halves (256x32)
  _Float16* BsB = ldsbuf + 4 * 8192;

  const int tid = threadIdx.x;
  const int lane = tid & 63, wave = tid >> 6;   // wave 0..15
  const int wm = wave >> 2, wn = wave & 3;      // 4M x 4N

  int bid = blockIdx.x;
  int swz = (bid & 7) * (1024 >> 3) + (bid >> 3);
  const int bmBase = (swz >> 4) * 256;
  const int bnBase = (swz & 15) * 256;

  const int s = tid ^ ((tid >> 3) & 3);
  const _Float16* aSrc = A + (size_t)(bmBase + (s >> 2)) * D_DIM + (s & 3) * 8;
  const _Float16* bSrc = Bt + (size_t)(bnBase + (s >> 2)) * D_DIM + (s & 3) * 8;
  const int dstL = tid * 8;

  const int fr = lane & 15, c4 = lane >> 4;
  const int swzc = (c4 ^ ((fr >> 1) & 3)) * 8;
  const int aBase = (wm * 64 + fr) * 32 + swzc;
  const int bBase = (wn * 64 + fr) * 32 + swzc;

  f32x4 acc[4][4];
  #pragma unroll
  for (int i = 0; i < 4; ++i)
    #pragma unroll
    for (int j = 0; j < 4; ++j) acc[i][j] = f32x4{0.f, 0.f, 0.f, 0.f};

  #pragma unroll
  for (int tt = 0; tt < 3; ++tt) {
    const int bo = tt * 8192, kk = tt * 32;
    gload_lds16(aSrc + kk, AsB + bo + dstL);
    gload_lds16(bSrc + kk, BsB + bo + dstL);
  }

  for (int t = 0; t < NTILES - 2; ++t) TILE_BODY(t, "vmcnt(4)");
  TILE_BODY(NTILES - 2, "vmcnt(2)");
  TILE_BODY(NTILES - 1, "vmcnt(0)");

  const int crow0 = bmBase + wm * 64 + c4 * 4;
  const int ccol0 = bnBase + wn * 64 + fr;
  #pragma unroll
  for (int mi = 0; mi < 4; ++mi)
    #pragma unroll
    for (int nj = 0; nj < 4; ++nj) {
      int col = ccol0 + nj * 16;
      float lb = latent_bias[col];
      #pragma unroll
      for (int r = 0; r < 4; ++r)
        C[(size_t)(crow0 + mi * 16 + r) * D_DIM + col] = acc[mi][nj][r] + lb;
    }
}

// ------------- fused two-level-histogram top-k + fp64 rescue ---------------
// Coarse: 256 bins x 4.0 over [-512,512) (clamped, monotone). bstar_c =
// largest bin with suffix >= 64 -> T64's coarse bin == bstar_c; rank within
// it r = 64 - suffix(bstar_c+1). Fine: 256 bins x 0.015625 inside the
// coarse bin; fstar = largest with in-bin suffix >= r -> T64 in [Tlo,Thi),
// width 0.0156 (inf fallbacks at clamped extremes). Members: v > Thi+M
// (provably in exact top-64, provably < 64 of them). Zone: [Tlo-M, Thi+M];
// M=0.25 covers 2x the fp16-GEMM error bound (validated R3..R10).
// Fast path: |zone| == need -> emit. Else fp64 dots in-kernel.

__global__ __launch_bounds__(256) void topk_full(
    const float* __restrict__ acts, const float* __restrict__ x,
    const float* __restrict__ WT, const float* __restrict__ pre_bias,
    const float* __restrict__ latent_bias, float* __restrict__ vals,
    int* __restrict__ idxs) {
  const int row = blockIdx.x;
  const int tid = threadIdx.x;
  const int lane = tid & 63, wave = tid >> 6;
  __shared__ int hist[256];
  __shared__ int suf[256];
  __shared__ int sred[8];
  __shared__ int ambL[128];
  __shared__ double exv[128];
  const float* arow = acts + (size_t)row * D_DIM;
  float fv[16];
  #pragma unroll
  for (int i = 0; i < 4; ++i) {
    float4 a = *(const float4*)(arow + i * 1024 + tid * 4);
    fv[4 * i + 0] = a.x; fv[4 * i + 1] = a.y;
    fv[4 * i + 2] = a.z; fv[4 * i + 3] = a.w;
  }
  // ---- coarse pass ----
  hist[tid] = 0;
  __syncthreads();
  #pragma unroll
  for (int e = 0; e < 16; ++e) {
    int b = (int)((fv[e] + 512.0f) * 0.25f);
    b = b < 0 ? 0 : (b > 255 ? 255 : b);
    atomicAdd(&hist[b], 1);
  }
  __syncthreads();
  int c = hist[tid];
  int sfx = c;
  #pragma unroll
  for (int off = 1; off < 64; off <<= 1) {
    int y = __shfl_down(sfx, off);
    if (lane + off < 64) sfx += y;
  }
  if (lane == 0) sred[wave] = sfx;
  __syncthreads();
  {
    int after = 0;
    for (int w = wave + 1; w < 4; ++w) after += sred[w];
    sfx += after;  // count of values in bins >= tid
  }
  suf[tid] = sfx;
  int cnd = (sfx >= TOPK) ? tid : -1;
  #pragma unroll
  for (int off = 32; off; off >>= 1) {
    int y = __shfl_down(cnd, off);
    cnd = y > cnd ? y : cnd;
  }
  if (lane == 0) sred[4 + wave] = cnd;
  __syncthreads();
  int cb;
  {
    int m0 = sred[4] > sred[5] ? sred[4] : sred[5];
    int m1 = sred[6] > sred[7] ? sred[6] : sred[7];
    cb = m0 > m1 ? m0 : m1;  // exists: suffix(0) = 4096 >= 64
  }
  const int S_above = (cb < 255) ? suf[cb + 1] : 0;
  const int rrank = TOPK - S_above;  // in [1, count(cb)]
  const float Clo = cb * 4.0f - 512.0f;
  // ---- fine pass (reuse hist/sred) ----
  __syncthreads();
  hist[tid] = 0;
  __syncthreads();
  #pragma unroll
  for (int e = 0; e < 16; ++e) {
    int bc = (int)((fv[e] + 512.0f) * 0.25f);
    bc = bc < 0 ? 0 : (bc > 255 ? 255 : bc);
    if (bc == cb) {
      int fb = (int)((fv[e] - Clo) * 64.0f);
      fb = fb < 0 ? 0 : (fb > 255 ? 255 : fb);
      atomicAdd(&hist[fb], 1);
    }
  }
  __syncthreads();
  int cf = hist[tid];
  int sfx2 = cf;
  #pragma unroll
  for (int off = 1; off < 64; off <<= 1) {
    int y = __shfl_down(sfx2, off);
    if (lane + off < 64) sfx2 += y;
  }
  if (lane == 0) sred[wave] = sfx2;
  __syncthreads();
  {
    int after = 0;
    for (int w = wave + 1; w < 4; ++w) after += sred[w];
    sfx2 += after;
  }
  int cnd2 = (sfx2 >= rrank) ? tid : -1;
  #pragma unroll
  for (int off = 32; off; off >>= 1) {
    int y = __shfl_down(cnd2, off);
    cnd2 = y > cnd2 ? y : cnd2;
  }
  if (lane == 0) sred[4 + wave] = cnd2;
  __syncthreads();
  int fb;
  {
    int m0 = sred[4] > sred[5] ? sred[4] : sred[5];
    int m1 = sred[6] > sred[7] ? sred[6] : sred[7];
    fb = m0 > m1 ? m0 : m1;  // exists: fine suffix(0) = count(cb) >= rrank
  }
  const float Tlo = (cb == 0 && fb == 0) ? -1e30f : (Clo + fb * 0.015625f);
  const float Thi =
      (cb == 255 && fb == 255) ? 1e30f : (Clo + (fb + 1) * 0.015625f);
  const float vhi = Thi + MARGIN;
  const float vlo = Tlo - MARGIN;
  // ---- classify + emit ----
  int mC = 0, aC = 0;
  #pragma unroll
  for (int i = 0; i < 16; ++i) {
    float v = fv[i];
    if (v > vhi) ++mC;
    else if (v >= vlo) ++aC;
  }
  int xs = mC | (aC << 16);
  #pragma unroll
  for (int off = 1; off < 64; off <<= 1) {
    int y = __shfl_up(xs, off);
    if (lane >= off) xs += y;
  }
  __syncthreads();  // sred reuse
  if (lane == 63) sred[wave] = xs;
  __syncthreads();
  int base = 0;
  for (int w = 0; w < 4; ++w)
    if (w < wave) base += sred[w];
  int tot = sred[0] + sred[1] + sred[2] + sred[3];
  int incl = base + xs;
  int mp = (incl & 0xffff) - mC;
  int ap = (incl >> 16) - aC;
  int mTot = tot & 0xffff, aTot = tot >> 16;
  const int need = TOPK - mTot;      // >= 1 provably
  const bool fast = (aTot == need);  // zone exactly fills the remainder
  #pragma unroll
  for (int e = 0; e < 16; ++e) {
    float v = fv[e];
    int d = (e >> 2) * 1024 + tid * 4 + (e & 3);
    if (v > vhi) {
      vals[(size_t)row * TOPK + mp] = fmaxf(v, 0.0f);
      idxs[(size_t)row * TOPK + mp] = d;
      ++mp;
    } else if (v >= vlo) {
      if (fast) {
        vals[(size_t)row * TOPK + mTot + ap] = fmaxf(v, 0.0f);
        idxs[(size_t)row * TOPK + mTot + ap] = d;
      } else if (ap < 128) {
        ambL[ap] = d;
      }
      ++ap;
    }
  }
  if (fast) return;
  // ---- fused fp64 rescue ----
  __syncthreads();  // ambL visible block-wide
  const int sN = aTot > 128 ? 128 : aTot;
  const float* xr = x + (size_t)row * D_DIM;
  for (int cc = wave; cc < sN; cc += 4) {
    int d = ambL[cc];
    const float* wrow = WT + (size_t)d * D_DIM;
    double acc = 0.0;
    #pragma unroll 4
    for (int t = 0; t < 16; ++t) {
      int k0 = t * 256 + lane * 4;
      float4 xv = *(const float4*)(xr + k0);
      float4 pv = *(const float4*)(pre_bias + k0);
      float4 wv = *(const float4*)(wrow + k0);
      acc = fma((double)xv.x - (double)pv.x, (double)wv.x, acc);
      acc = fma((double)xv.y - (double)pv.y, (double)wv.y, acc);
      acc = fma((double)xv.z - (double)pv.z, (double)wv.z, acc);
      acc = fma((double)xv.w - (double)pv.w, (double)wv.w, acc);
    }
    #pragma unroll
    for (int off = 32; off; off >>= 1) acc += __shfl_down(acc, off);
    if (lane == 0) exv[cc] = acc + (double)latent_bias[d];
  }
  __syncthreads();
  if (tid == 0) {
    for (int t = 0; t < need; ++t) {
      double best = -1.0e300; int besti = 1 << 30; int bestc = -1;
      for (int cc = 0; cc < sN; ++cc) {
        double v = exv[cc];
        int d = ambL[cc];
        if (v > best || (v == best && d < besti)) {
          best = v; besti = d; bestc = cc;
        }
      }
      vals[(size_t)row * TOPK + mTot + t] = fmaxf((float)best, 0.0f);
      idxs[(size_t)row * TOPK + mTot + t] = besti;
      exv[bestc] = -1.0e300;
    }
  }
}

// ----------------------------- reconstruct ---------------------------------

__global__ __launch_bounds__(256) void reconstruct(
    const unsigned short* __restrict__ Wd, const float* __restrict__ vals,
    const int* __restrict__ idxs, const float* __restrict__ pre_bias,
    float* __restrict__ out) {
  const int bid = blockIdx.x;
  const int cb = bid & 7, rowblk = bid >> 3;
  const int tid = threadIdx.x, lane = tid & 63, wave = tid >> 6;
  const int row = rowblk * 4 + wave;
  const int col0 = cb * 512 + lane * 8;
  __shared__ float sval[256];
  __shared__ int sidx[256];
  sval[tid] = vals[(size_t)(rowblk * 4 + (tid >> 6)) * TOPK + (tid & 63)];
  sidx[tid] = idxs[(size_t)(rowblk * 4 + (tid >> 6)) * TOPK + (tid & 63)];
  __syncthreads();
  float acc[8];
  float4 p0 = *(const float4*)(pre_bias + col0);
  float4 p1 = *(const float4*)(pre_bias + col0 + 4);
  acc[0] = p0.x; acc[1] = p0.y; acc[2] = p0.z; acc[3] = p0.w;
  acc[4] = p1.x; acc[5] = p1.y; acc[6] = p1.z; acc[7] = p1.w;
  #pragma unroll 4
  for (int k = 0; k < TOPK; ++k) {
    float v = sval[wave * 64 + k];
    int d = sidx[wave * 64 + k];
    ushort8 w = *(const ushort8*)(Wd + (size_t)d * D_DIM + col0);
    #pragma unroll
    for (int j = 0; j < 8; ++j)
      acc[j] = fmaf(v, __uint_as_float(((unsigned)w[j]) << 16), acc[j]);
  }
  float4 o0 = {acc[0], acc[1], acc[2], acc[3]};
  float4 o1 = {acc[4], acc[5], acc[6], acc[7]};
  *(float4*)(out + (size_t)row * D_DIM + col0) = o0;
  *(float4*)(out + (size_t)row * D_DIM + col0 + 4) = o1;
}

// ------------------------------- launcher ----------------------------------

extern "C" void kernel_launch(void* const* d_in, const int* in_sizes, int n_in,
                              void* d_out, int out_size, void* d_ws,
                              size_t ws_size, hipStream_t stream) {
  const float* x           = (const float*)d_in[0];
  // d_in[1] = ema_frequency_counter (unused by reference)
  const float* W_enc       = (const float*)d_in[2];
  const float* W_dec       = (const float*)d_in[3];
  const float* pre_bias    = (const float*)d_in[4];
  const float* latent_bias = (const float*)d_in[5];
  float* out = (float*)d_out;  // doubles as acts buffer, overwritten last
  char* ws = (char*)d_ws;
  size_t off = 0;
  auto alloc = [&](size_t bytes) {
    size_t o = off;
    off = (off + bytes + 255) & ~(size_t)255;
    return o;
  };
  _Float16* Xh        = (_Float16*)(ws + alloc((size_t)B_ROWS * D_DIM * 2));
  _Float16* WhT       = (_Float16*)(ws + alloc((size_t)D_DIM * D_DIM * 2));
  float* WT           = (float*)(ws + alloc((size_t)D_DIM * D_DIM * 4));
  unsigned short* Wd  = (unsigned short*)(ws + alloc((size_t)D_DIM * D_DIM * 2));
  float* vals         = (float*)(ws + alloc((size_t)B_ROWS * TOPK * 4));
  int* idxs           = (int*)(ws + alloc((size_t)B_ROWS * TOPK * 4));
  (void)ws_size; (void)in_sizes; (void)n_in; (void)out_size;

  // allow 128KB dynamic LDS for the GEMM (cheap, deterministic, idempotent)
  (void)hipFuncSetAttribute((const void*)gemm_f16,
                            hipFuncAttributeMaxDynamicSharedMemorySize,
                            131072);

  conv_x<<<(B_ROWS * D_DIM / 8) / 256, 256, 0, stream>>>(x, pre_bias, Xh);
  transp_w<<<dim3(D_DIM / 64, D_DIM / 64), 256, 0, stream>>>(W_enc, WhT, WT);
  conv_wd<<<((size_t)D_DIM * D_DIM / 8) / 256, 256, 0, stream>>>(W_dec, Wd);
  gemm_f16<<<(B_ROWS / 256) * (D_DIM / 256), 1024, 131072, stream>>>(
      Xh, WhT, latent_bias, out);
  topk_full<<<B_ROWS, 256, 0, stream>>>(out, x, WT, pre_bias, latent_bias,
                                        vals, idxs);
  reconstruct<<<(B_ROWS / 4) * 8, 256, 0, stream>>>(Wd, vals, idxs, pre_bias,
                                                    out);
}

// Round 12
// 1099.732 us; speedup vs baseline: 1.0630x; 1.0443x over previous
//
#include <hip/hip_runtime.h>
#include <hip/hip_bf16.h>
#include <stdint.h>

// ---------------------------------------------------------------------------
// TopKAutoEncoder forward, MI355X.
// acts = (x - pre_bias) @ W_enc + latent_bias   [16384 x 4096]
// top-64/row (exact selection vs ref), relu, @ W_dec + pre_bias.
//
// GEMM (R10 best): 256x256 tile, 1024 thr / 16 waves (4Mx4N, 64x64 out,
// 4 waves/SIMD), BK=32, 4-deep LDS pipeline, counted vmcnt(4/2/0),
// chunk-XOR swizzle (0 bank conflicts), XCD swizzle, setprio.
// R12: acts stored FP16 in d_out's first half (halves the acts HBM
// round-trip; quantization +-0.0625 absorbed by MARGIN=0.25 alongside the
// fp16-GEMM error bound ~0.16; reconstruct later overwrites full f32 out).
// topk_full: two-level histogram (256x4.0 + 256x0.015625) + fused fp64
// boundary rescue. bf16 sparse reconstruct, XCD-L2-resident W_dec slabs.
// ---------------------------------------------------------------------------

typedef _Float16 half8 __attribute__((ext_vector_type(8)));
typedef float f32x4 __attribute__((ext_vector_type(4)));
typedef unsigned short ushort8 __attribute__((ext_vector_type(8)));

#define B_ROWS 16384
#define D_DIM  4096
#define TOPK   64
#define MARGIN 0.25f
#define NTILES (D_DIM / 32)

__device__ __forceinline__ void gload_lds16(const void* g, void* l) {
  __builtin_amdgcn_global_load_lds(
      (const __attribute__((address_space(1))) unsigned int*)g,
      (__attribute__((address_space(3))) unsigned int*)l, 16, 0, 0);
}

__device__ __forceinline__ unsigned short f2bf(float f) {
  unsigned u = __float_as_uint(f);
  unsigned r = (u + 0x7fffu + ((u >> 16) & 1u)) >> 16;
  return (unsigned short)r;
}

// --------------------------- conversion kernels ----------------------------

__global__ __launch_bounds__(256) void conv_x(
    const float* __restrict__ x, const float* __restrict__ pre_bias,
    _Float16* __restrict__ Xh) {
  size_t g = ((size_t)blockIdx.x * 256 + threadIdx.x) * 8;
  int col = (int)(g & (D_DIM - 1));
  float4 a = *(const float4*)(x + g);
  float4 b = *(const float4*)(x + g + 4);
  float4 p = *(const float4*)(pre_bias + col);
  float4 q = *(const float4*)(pre_bias + col + 4);
  half8 h;
  h[0] = (_Float16)(a.x - p.x); h[1] = (_Float16)(a.y - p.y);
  h[2] = (_Float16)(a.z - p.z); h[3] = (_Float16)(a.w - p.w);
  h[4] = (_Float16)(b.x - q.x); h[5] = (_Float16)(b.y - q.y);
  h[6] = (_Float16)(b.z - q.z); h[7] = (_Float16)(b.w - q.w);
  *(half8*)(Xh + g) = h;
}

// W_enc [K][N] fp32 -> WhT [N][K] fp16  AND WT [N][K] fp32 (for fp64 rescue)
__global__ __launch_bounds__(256) void transp_w(
    const float* __restrict__ W, _Float16* __restrict__ WhT,
    float* __restrict__ WT) {
  __shared__ float tile[64][65];
  int bx = blockIdx.x, by = blockIdx.y;
  int tx = threadIdx.x & 63, ty4 = threadIdx.x >> 6;
  #pragma unroll 4
  for (int i = 0; i < 16; ++i) {
    int r = ty4 * 16 + i;
    tile[r][tx] = W[(size_t)(by * 64 + r) * D_DIM + bx * 64 + tx];
  }
  __syncthreads();
  #pragma unroll 4
  for (int i = 0; i < 16; ++i) {
    int r = ty4 * 16 + i;
    float v = tile[tx][r];
    size_t o = (size_t)(bx * 64 + r) * D_DIM + by * 64 + tx;
    WT[o] = v;
    WhT[o] = (_Float16)v;
  }
}

__global__ __launch_bounds__(256) void conv_wd(
    const float* __restrict__ W, unsigned short* __restrict__ o) {
  size_t g = ((size_t)blockIdx.x * 256 + threadIdx.x) * 8;
  float4 a = *(const float4*)(W + g);
  float4 b = *(const float4*)(W + g + 4);
  ushort8 v;
  v[0] = f2bf(a.x); v[1] = f2bf(a.y); v[2] = f2bf(a.z); v[3] = f2bf(a.w);
  v[4] = f2bf(b.x); v[5] = f2bf(b.y); v[6] = f2bf(b.z); v[7] = f2bf(b.w);
  *(ushort8*)(o + g) = v;
}

// ------------------------------- fp16 GEMM (R10, fp16 C out) ---------------

#define TILE_BODY(T, VMSTR)                                                    \
  do {                                                                         \
    asm volatile("s_waitcnt " VMSTR ::: "memory");                             \
    __builtin_amdgcn_s_barrier();                                              \
    asm volatile("" ::: "memory");                                             \
    const int tt3 = (T) + 3;                                                   \
    if (tt3 < NTILES) {                                                        \
      const int bo = (tt3 & 3) * 8192;                                         \
      const int kk = tt3 * 32;                                                 \
      gload_lds16(aSrc + kk, AsB + bo + dstL);                                 \
      gload_lds16(bSrc + kk, BsB + bo + dstL);                                 \
    }                                                                          \
    {                                                                          \
      const int ab = ((T) & 3) * 8192;                                         \
      half8 bf[4], af[4];                                                      \
      _Pragma("unroll") for (int nj = 0; nj < 4; ++nj)                         \
          bf[nj] = *(const half8*)(BsB + ab + bBase + nj * 512);               \
      _Pragma("unroll") for (int mi = 0; mi < 4; ++mi)                         \
          af[mi] = *(const half8*)(AsB + ab + aBase + mi * 512);               \
      __builtin_amdgcn_s_setprio(1);                                           \
      _Pragma("unroll") for (int mi = 0; mi < 4; ++mi)                         \
          _Pragma("unroll") for (int nj = 0; nj < 4; ++nj)                     \
          acc[mi][nj] = __builtin_amdgcn_mfma_f32_16x16x32_f16(                \
              af[mi], bf[nj], acc[mi][nj], 0, 0, 0);                           \
      __builtin_amdgcn_s_setprio(0);                                           \
    }                                                                          \
  } while (0)

__global__ __launch_bounds__(1024, 4) void gemm_f16(
    const _Float16* __restrict__ A, const _Float16* __restrict__ Bt,
    const float* __restrict__ latent_bias, _Float16* __restrict__ C) {
  extern __shared__ _Float16 ldsbuf[];
  _Float16* AsB = ldsbuf;            // 4 bufs x 8192 halves (256x32)
  _Float16* BsB = ldsbuf + 4 * 8192;

  const int tid = threadIdx.x;
  const int lane = tid & 63, wave = tid >> 6;   // wave 0..15
  const int wm = wave >> 2, wn = wave & 3;      // 4M x 4N

  int bid = blockIdx.x;
  int swz = (bid & 7) * (1024 >> 3) + (bid >> 3);
  const int bmBase = (swz >> 4) * 256;
  const int bnBase = (swz & 15) * 256;

  const int s = tid ^ ((tid >> 3) & 3);
  const _Float16* aSrc = A + (size_t)(bmBase + (s >> 2)) * D_DIM + (s & 3) * 8;
  const _Float16* bSrc = Bt + (size_t)(bnBase + (s >> 2)) * D_DIM + (s & 3) * 8;
  const int dstL = tid * 8;

  const int fr = lane & 15, c4 = lane >> 4;
  const int swzc = (c4 ^ ((fr >> 1) & 3)) * 8;
  const int aBase = (wm * 64 + fr) * 32 + swzc;
  const int bBase = (wn * 64 + fr) * 32 + swzc;

  f32x4 acc[4][4];
  #pragma unroll
  for (int i = 0; i < 4; ++i)
    #pragma unroll
    for (int j = 0; j < 4; ++j) acc[i][j] = f32x4{0.f, 0.f, 0.f, 0.f};

  #pragma unroll
  for (int tt = 0; tt < 3; ++tt) {
    const int bo = tt * 8192, kk = tt * 32;
    gload_lds16(aSrc + kk, AsB + bo + dstL);
    gload_lds16(bSrc + kk, BsB + bo + dstL);
  }

  for (int t = 0; t < NTILES - 2; ++t) TILE_BODY(t, "vmcnt(4)");
  TILE_BODY(NTILES - 2, "vmcnt(2)");
  TILE_BODY(NTILES - 1, "vmcnt(0)");

  const int crow0 = bmBase + wm * 64 + c4 * 4;
  const int ccol0 = bnBase + wn * 64 + fr;
  #pragma unroll
  for (int mi = 0; mi < 4; ++mi)
    #pragma unroll
    for (int nj = 0; nj < 4; ++nj) {
      int col = ccol0 + nj * 16;
      float lb = latent_bias[col];
      #pragma unroll
      for (int r = 0; r < 4; ++r)
        C[(size_t)(crow0 + mi * 16 + r) * D_DIM + col] =
            (_Float16)(acc[mi][nj][r] + lb);
    }
}

// ------------- fused two-level-histogram top-k + fp64 rescue ---------------
// acts are fp16 (quantization +-0.0625 at |v|<256); histogram and classify
// consistently use quantized values; MARGIN=0.25 covers GEMM error (~0.16
// 6-sigma bound) + quantization. Coarse 256 x 4.0 -> rank-refined fine
// 256 x 0.015625 -> T64 bracket [Tlo,Thi). Members: v > Thi+M (provably in
// exact top-64, provably < 64). Zone: [Tlo-M, Thi+M]. Fast path:
// |zone| == need -> emit. Else fp64 dots in-kernel (wave-per-candidate).

__global__ __launch_bounds__(256) void topk_full(
    const _Float16* __restrict__ acts, const float* __restrict__ x,
    const float* __restrict__ WT, const float* __restrict__ pre_bias,
    const float* __restrict__ latent_bias, float* __restrict__ vals,
    int* __restrict__ idxs) {
  const int row = blockIdx.x;
  const int tid = threadIdx.x;
  const int lane = tid & 63, wave = tid >> 6;
  __shared__ int hist[256];
  __shared__ int suf[256];
  __shared__ int sred[8];
  __shared__ int ambL[128];
  __shared__ double exv[128];
  const _Float16* arow = acts + (size_t)row * D_DIM;
  float fv[16];
  {
    half8 h0 = *(const half8*)(arow + tid * 8);
    half8 h1 = *(const half8*)(arow + 2048 + tid * 8);
    #pragma unroll
    for (int j = 0; j < 8; ++j) {
      fv[j] = (float)h0[j];
      fv[8 + j] = (float)h1[j];
    }
  }
  // index of element e of this thread:
  //   e<8: tid*8+e ; e>=8: 2048 + tid*8 + (e-8)
  // ---- coarse pass ----
  hist[tid] = 0;
  __syncthreads();
  #pragma unroll
  for (int e = 0; e < 16; ++e) {
    int b = (int)((fv[e] + 512.0f) * 0.25f);
    b = b < 0 ? 0 : (b > 255 ? 255 : b);
    atomicAdd(&hist[b], 1);
  }
  __syncthreads();
  int c = hist[tid];
  int sfx = c;
  #pragma unroll
  for (int off = 1; off < 64; off <<= 1) {
    int y = __shfl_down(sfx, off);
    if (lane + off < 64) sfx += y;
  }
  if (lane == 0) sred[wave] = sfx;
  __syncthreads();
  {
    int after = 0;
    for (int w = wave + 1; w < 4; ++w) after += sred[w];
    sfx += after;  // count of values in bins >= tid
  }
  suf[tid] = sfx;
  int cnd = (sfx >= TOPK) ? tid : -1;
  #pragma unroll
  for (int off = 32; off; off >>= 1) {
    int y = __shfl_down(cnd, off);
    cnd = y > cnd ? y : cnd;
  }
  if (lane == 0) sred[4 + wave] = cnd;
  __syncthreads();
  int cb;
  {
    int m0 = sred[4] > sred[5] ? sred[4] : sred[5];
    int m1 = sred[6] > sred[7] ? sred[6] : sred[7];
    cb = m0 > m1 ? m0 : m1;  // exists: suffix(0) = 4096 >= 64
  }
  const int S_above = (cb < 255) ? suf[cb + 1] : 0;
  const int rrank = TOPK - S_above;  // in [1, count(cb)]
  const float Clo = cb * 4.0f - 512.0f;
  // ---- fine pass (reuse hist/sred) ----
  __syncthreads();
  hist[tid] = 0;
  __syncthreads();
  #pragma unroll
  for (int e = 0; e < 16; ++e) {
    int bc = (int)((fv[e] + 512.0f) * 0.25f);
    bc = bc < 0 ? 0 : (bc > 255 ? 255 : bc);
    if (bc == cb) {
      int fb = (int)((fv[e] - Clo) * 64.0f);
      fb = fb < 0 ? 0 : (fb > 255 ? 255 : fb);
      atomicAdd(&hist[fb], 1);
    }
  }
  __syncthreads();
  int cf = hist[tid];
  int sfx2 = cf;
  #pragma unroll
  for (int off = 1; off < 64; off <<= 1) {
    int y = __shfl_down(sfx2, off);
    if (lane + off < 64) sfx2 += y;
  }
  if (lane == 0) sred[wave] = sfx2;
  __syncthreads();
  {
    int after = 0;
    for (int w = wave + 1; w < 4; ++w) after += sred[w];
    sfx2 += after;
  }
  int cnd2 = (sfx2 >= rrank) ? tid : -1;
  #pragma unroll
  for (int off = 32; off; off >>= 1) {
    int y = __shfl_down(cnd2, off);
    cnd2 = y > cnd2 ? y : cnd2;
  }
  if (lane == 0) sred[4 + wave] = cnd2;
  __syncthreads();
  int fb;
  {
    int m0 = sred[4] > sred[5] ? sred[4] : sred[5];
    int m1 = sred[6] > sred[7] ? sred[6] : sred[7];
    fb = m0 > m1 ? m0 : m1;  // exists: fine suffix(0) = count(cb) >= rrank
  }
  const float Tlo = (cb == 0 && fb == 0) ? -1e30f : (Clo + fb * 0.015625f);
  const float Thi =
      (cb == 255 && fb == 255) ? 1e30f : (Clo + (fb + 1) * 0.015625f);
  const float vhi = Thi + MARGIN;
  const float vlo = Tlo - MARGIN;
  // ---- classify + emit ----
  int mC = 0, aC = 0;
  #pragma unroll
  for (int i = 0; i < 16; ++i) {
    float v = fv[i];
    if (v > vhi) ++mC;
    else if (v >= vlo) ++aC;
  }
  int xs = mC | (aC << 16);
  #pragma unroll
  for (int off = 1; off < 64; off <<= 1) {
    int y = __shfl_up(xs, off);
    if (lane >= off) xs += y;
  }
  __syncthreads();  // sred reuse
  if (lane == 63) sred[wave] = xs;
  __syncthreads();
  int base = 0;
  for (int w = 0; w < 4; ++w)
    if (w < wave) base += sred[w];
  int tot = sred[0] + sred[1] + sred[2] + sred[3];
  int incl = base + xs;
  int mp = (incl & 0xffff) - mC;
  int ap = (incl >> 16) - aC;
  int mTot = tot & 0xffff, aTot = tot >> 16;
  const int need = TOPK - mTot;      // >= 1 provably
  const bool fast = (aTot == need);  // zone exactly fills the remainder
  #pragma unroll
  for (int e = 0; e < 16; ++e) {
    float v = fv[e];
    int d = (e < 8) ? (tid * 8 + e) : (2048 + tid * 8 + (e - 8));
    if (v > vhi) {
      vals[(size_t)row * TOPK + mp] = fmaxf(v, 0.0f);
      idxs[(size_t)row * TOPK + mp] = d;
      ++mp;
    } else if (v >= vlo) {
      if (fast) {
        vals[(size_t)row * TOPK + mTot + ap] = fmaxf(v, 0.0f);
        idxs[(size_t)row * TOPK + mTot + ap] = d;
      } else if (ap < 128) {
        ambL[ap] = d;
      }
      ++ap;
    }
  }
  if (fast) return;
  // ---- fused fp64 rescue ----
  __syncthreads();  // ambL visible block-wide
  const int sN = aTot > 128 ? 128 : aTot;
  const float* xr = x + (size_t)row * D_DIM;
  for (int cc = wave; cc < sN; cc += 4) {
    int d = ambL[cc];
    const float* wrow = WT + (size_t)d * D_DIM;
    double acc = 0.0;
    #pragma unroll 4
    for (int t = 0; t < 16; ++t) {
      int k0 = t * 256 + lane * 4;
      float4 xv = *(const float4*)(xr + k0);
      float4 pv = *(const float4*)(pre_bias + k0);
      float4 wv = *(const float4*)(wrow + k0);
      acc = fma((double)xv.x - (double)pv.x, (double)wv.x, acc);
      acc = fma((double)xv.y - (double)pv.y, (double)wv.y, acc);
      acc = fma((double)xv.z - (double)pv.z, (double)wv.z, acc);
      acc = fma((double)xv.w - (double)pv.w, (double)wv.w, acc);
    }
    #pragma unroll
    for (int off = 32; off; off >>= 1) acc += __shfl_down(acc, off);
    if (lane == 0) exv[cc] = acc + (double)latent_bias[d];
  }
  __syncthreads();
  if (tid == 0) {
    for (int t = 0; t < need; ++t) {
      double best = -1.0e300; int besti = 1 << 30; int bestc = -1;
      for (int cc = 0; cc < sN; ++cc) {
        double v = exv[cc];
        int d = ambL[cc];
        if (v > best || (v == best && d < besti)) {
          best = v; besti = d; bestc = cc;
        }
      }
      vals[(size_t)row * TOPK + mTot + t] = fmaxf((float)best, 0.0f);
      idxs[(size_t)row * TOPK + mTot + t] = besti;
      exv[bestc] = -1.0e300;
    }
  }
}

// ----------------------------- reconstruct ---------------------------------

__global__ __launch_bounds__(256) void reconstruct(
    const unsigned short* __restrict__ Wd, const float* __restrict__ vals,
    const int* __restrict__ idxs, const float* __restrict__ pre_bias,
    float* __restrict__ out) {
  const int bid = blockIdx.x;
  const int cb = bid & 7, rowblk = bid >> 3;
  const int tid = threadIdx.x, lane = tid & 63, wave = tid >> 6;
  const int row = rowblk * 4 + wave;
  const int col0 = cb * 512 + lane * 8;
  __shared__ float sval[256];
  __shared__ int sidx[256];
  sval[tid] = vals[(size_t)(rowblk * 4 + (tid >> 6)) * TOPK + (tid & 63)];
  sidx[tid] = idxs[(size_t)(rowblk * 4 + (tid >> 6)) * TOPK + (tid & 63)];
  __syncthreads();
  float acc[8];
  float4 p0 = *(const float4*)(pre_bias + col0);
  float4 p1 = *(const float4*)(pre_bias + col0 + 4);
  acc[0] = p0.x; acc[1] = p0.y; acc[2] = p0.z; acc[3] = p0.w;
  acc[4] = p1.x; acc[5] = p1.y; acc[6] = p1.z; acc[7] = p1.w;
  #pragma unroll 4
  for (int k = 0; k < TOPK; ++k) {
    float v = sval[wave * 64 + k];
    int d = sidx[wave * 64 + k];
    ushort8 w = *(const ushort8*)(Wd + (size_t)d * D_DIM + col0);
    #pragma unroll
    for (int j = 0; j < 8; ++j)
      acc[j] = fmaf(v, __uint_as_float(((unsigned)w[j]) << 16), acc[j]);
  }
  float4 o0 = {acc[0], acc[1], acc[2], acc[3]};
  float4 o1 = {acc[4], acc[5], acc[6], acc[7]};
  *(float4*)(out + (size_t)row * D_DIM + col0) = o0;
  *(float4*)(out + (size_t)row * D_DIM + col0 + 4) = o1;
}

// ------------------------------- launcher ----------------------------------

extern "C" void kernel_launch(void* const* d_in, const int* in_sizes, int n_in,
                              void* d_out, int out_size, void* d_ws,
                              size_t ws_size, hipStream_t stream) {
  const float* x           = (const float*)d_in[0];
  // d_in[1] = ema_frequency_counter (unused by reference)
  const float* W_enc       = (const float*)d_in[2];
  const float* W_dec       = (const float*)d_in[3];
  const float* pre_bias    = (const float*)d_in[4];
  const float* latent_bias = (const float*)d_in[5];
  float* out = (float*)d_out;
  // fp16 acts alias d_out's first half (134 MB of the 268 MB f32 buffer);
  // fully consumed by topk_full before reconstruct overwrites all of out.
  _Float16* actsH = (_Float16*)d_out;
  char* ws = (char*)d_ws;
  size_t off = 0;
  auto alloc = [&](size_t bytes) {
    size_t o = off;
    off = (off + bytes + 255) & ~(size_t)255;
    return o;
  };
  _Float16* Xh        = (_Float16*)(ws + alloc((size_t)B_ROWS * D_DIM * 2));
  _Float16* WhT       = (_Float16*)(ws + alloc((size_t)D_DIM * D_DIM * 2));
  float* WT           = (float*)(ws + alloc((size_t)D_DIM * D_DIM * 4));
  unsigned short* Wd  = (unsigned short*)(ws + alloc((size_t)D_DIM * D_DIM * 2));
  float* vals         = (float*)(ws + alloc((size_t)B_ROWS * TOPK * 4));
  int* idxs           = (int*)(ws + alloc((size_t)B_ROWS * TOPK * 4));
  (void)ws_size; (void)in_sizes; (void)n_in; (void)out_size;

  // allow 128KB dynamic LDS for the GEMM (cheap, deterministic, idempotent)
  (void)hipFuncSetAttribute((const void*)gemm_f16,
                            hipFuncAttributeMaxDynamicSharedMemorySize,
                            131072);

  conv_x<<<(B_ROWS * D_DIM / 8) / 256, 256, 0, stream>>>(x, pre_bias, Xh);
  transp_w<<<dim3(D_DIM / 64, D_DIM / 64), 256, 0, stream>>>(W_enc, WhT, WT);
  conv_wd<<<((size_t)D_DIM * D_DIM / 8) / 256, 256, 0, stream>>>(W_dec, Wd);
  gemm_f16<<<(B_ROWS / 256) * (D_DIM / 256), 1024, 131072, stream>>>(
      Xh, WhT, latent_bias, actsH);
  topk_full<<<B_ROWS, 256, 0, stream>>>(actsH, x, WT, pre_bias, latent_bias,
                                        vals, idxs);
  reconstruct<<<(B_ROWS / 4) * 8, 256, 0, stream>>>(Wd, vals, idxs, pre_bias,
                                                    out);
}

// Round 13
// 1078.687 us; speedup vs baseline: 1.0838x; 1.0195x over previous
//
#include <hip/hip_runtime.h>
#include <hip/hip_bf16.h>
#include <stdint.h>

// ---------------------------------------------------------------------------
// TopKAutoEncoder forward, MI355X.
// acts = (x - pre_bias) @ W_enc + latent_bias   [16384 x 4096]
// top-64/row (exact selection vs ref), relu, @ W_dec + pre_bias.
//
// R13 GEMM: 256x256 tile, 1024 thr / 16 waves (4Mx4N, 64x64 out), BK=64
// K-tiles (64 of them), 2-buffer LDS pipeline (2 x 64KB), ONE barrier +
// one (already-satisfied) vmcnt(0) per tile -- half the sync events of
// BK=32. Chunk-XOR swizzle per 32-K half (0 bank conflicts), XCD swizzle,
// setprio. acts stored fp16 into d_out's first half.
// Merged preprocess kernel (conv_x + transp_w + conv_wd, grid-partitioned).
// topk_full: two-level histogram + fused fp64 boundary rescue.
// bf16 sparse reconstruct with XCD-L2-resident W_dec slabs.
// ---------------------------------------------------------------------------

typedef _Float16 half8 __attribute__((ext_vector_type(8)));
typedef float f32x4 __attribute__((ext_vector_type(4)));
typedef unsigned short ushort8 __attribute__((ext_vector_type(8)));

#define B_ROWS 16384
#define D_DIM  4096
#define TOPK   64
#define MARGIN 0.25f
#define KT64   (D_DIM / 64)   // 64 K-tiles of BK=64

__device__ __forceinline__ void gload_lds16(const void* g, void* l) {
  __builtin_amdgcn_global_load_lds(
      (const __attribute__((address_space(1))) unsigned int*)g,
      (__attribute__((address_space(3))) unsigned int*)l, 16, 0, 0);
}

__device__ __forceinline__ unsigned short f2bf(float f) {
  unsigned u = __float_as_uint(f);
  unsigned r = (u + 0x7fffu + ((u >> 16) & 1u)) >> 16;
  return (unsigned short)r;
}

// --------------------- merged preprocess (one launch) ----------------------
// blocks [0, 32768):   conv_x   -- Xh = fp16(x - pre_bias)
// blocks [32768,36864): transp_w -- WhT/WT = W_enc^T (fp16 + fp32)
// blocks [36864,45056): conv_wd  -- Wd = bf16(W_dec)

__global__ __launch_bounds__(256) void preprocess(
    const float* __restrict__ x, const float* __restrict__ pre_bias,
    const float* __restrict__ W_enc, const float* __restrict__ W_dec,
    _Float16* __restrict__ Xh, _Float16* __restrict__ WhT,
    float* __restrict__ WT, unsigned short* __restrict__ Wd) {
  __shared__ float tile[64][65];
  const int bid = blockIdx.x;
  const int tid = threadIdx.x;
  if (bid < 32768) {
    size_t g = ((size_t)bid * 256 + tid) * 8;
    int col = (int)(g & (D_DIM - 1));
    float4 a = *(const float4*)(x + g);
    float4 b = *(const float4*)(x + g + 4);
    float4 p = *(const float4*)(pre_bias + col);
    float4 q = *(const float4*)(pre_bias + col + 4);
    half8 h;
    h[0] = (_Float16)(a.x - p.x); h[1] = (_Float16)(a.y - p.y);
    h[2] = (_Float16)(a.z - p.z); h[3] = (_Float16)(a.w - p.w);
    h[4] = (_Float16)(b.x - q.x); h[5] = (_Float16)(b.y - q.y);
    h[6] = (_Float16)(b.z - q.z); h[7] = (_Float16)(b.w - q.w);
    *(half8*)(Xh + g) = h;
  } else if (bid < 36864) {
    const int b2 = bid - 32768;
    const int bx = b2 & 63, by = b2 >> 6;
    const int tx = tid & 63, ty4 = tid >> 6;
    #pragma unroll 4
    for (int i = 0; i < 16; ++i) {
      int r = ty4 * 16 + i;
      tile[r][tx] = W_enc[(size_t)(by * 64 + r) * D_DIM + bx * 64 + tx];
    }
    __syncthreads();
    #pragma unroll 4
    for (int i = 0; i < 16; ++i) {
      int r = ty4 * 16 + i;
      float v = tile[tx][r];
      size_t o = (size_t)(bx * 64 + r) * D_DIM + by * 64 + tx;
      WT[o] = v;
      WhT[o] = (_Float16)v;
    }
  } else {
    size_t g = ((size_t)(bid - 36864) * 256 + tid) * 8;
    float4 a = *(const float4*)(W_dec + g);
    float4 b = *(const float4*)(W_dec + g + 4);
    ushort8 v;
    v[0] = f2bf(a.x); v[1] = f2bf(a.y); v[2] = f2bf(a.z); v[3] = f2bf(a.w);
    v[4] = f2bf(b.x); v[5] = f2bf(b.y); v[6] = f2bf(b.z); v[7] = f2bf(b.w);
    *(ushort8*)(Wd + g) = v;
  }
}

// ------------------------------- fp16 GEMM ---------------------------------
// LDS (halves): buffer d at d*32768. Within a buffer: A kh at kh*8192,
// B kh at 16384 + kh*8192 (kh = K-half of 32). Per-kh layout identical to
// the verified R10 structure: 1024 slots of 8 halves; phys slot i holds
// logical chunk i^((i>>3)&3); read chunk c of row r at phys c^((r>>1)&3)
// (0 bank conflicts, verified R3..R12).
// Body t: issue STAGE(t+1) [4 loads into buf (t+1)&1]; compute both
// K-halves of tile t from buf t&1; vmcnt(0) [stage(t+1) issued ~3000 cyc
// ago -> drain ~free]; barrier. Readers of buf (t+1)&1 (body t-1) finished
// before the end-of-body-(t-1) barrier (MFMA lgkm deps precede it), so the
// staging write is race-free; prologue keeps wait->barrier (R4 lesson).

#define STAGE64(T)                                                             \
  do {                                                                         \
    const int bb_ = ((T) & 1) * 32768;                                         \
    const int kk_ = (T) * 64;                                                  \
    gload_lds16(aSrc + kk_, ldsbuf + bb_ + dstL);                              \
    gload_lds16(aSrc + kk_ + 32, ldsbuf + bb_ + 8192 + dstL);                  \
    gload_lds16(bSrc + kk_, ldsbuf + bb_ + 16384 + dstL);                      \
    gload_lds16(bSrc + kk_ + 32, ldsbuf + bb_ + 24576 + dstL);                 \
  } while (0)

#define HALF_COMPUTE(T, KH)                                                    \
  do {                                                                         \
    const int ab_ = ((T) & 1) * 32768 + (KH) * 8192;                           \
    half8 bf[4], af[4];                                                        \
    _Pragma("unroll") for (int nj = 0; nj < 4; ++nj)                           \
        bf[nj] = *(const half8*)(ldsbuf + ab_ + 16384 + bBase + nj * 512);     \
    _Pragma("unroll") for (int mi = 0; mi < 4; ++mi)                           \
        af[mi] = *(const half8*)(ldsbuf + ab_ + aBase + mi * 512);             \
    __builtin_amdgcn_s_setprio(1);                                             \
    _Pragma("unroll") for (int mi = 0; mi < 4; ++mi)                           \
        _Pragma("unroll") for (int nj = 0; nj < 4; ++nj)                       \
        acc[mi][nj] = __builtin_amdgcn_mfma_f32_16x16x32_f16(                  \
            af[mi], bf[nj], acc[mi][nj], 0, 0, 0);                             \
    __builtin_amdgcn_s_setprio(0);                                             \
  } while (0)

#define BODY64(T, DOSTAGE)                                                     \
  do {                                                                         \
    if (DOSTAGE) STAGE64((T) + 1);                                             \
    HALF_COMPUTE(T, 0);                                                        \
    HALF_COMPUTE(T, 1);                                                        \
    asm volatile("s_waitcnt vmcnt(0)" ::: "memory");                           \
    __builtin_amdgcn_s_barrier();                                              \
    asm volatile("" ::: "memory");                                             \
  } while (0)

__global__ __launch_bounds__(1024, 4) void gemm_f16(
    const _Float16* __restrict__ A, const _Float16* __restrict__ Bt,
    const float* __restrict__ latent_bias, _Float16* __restrict__ C) {
  extern __shared__ _Float16 ldsbuf[];   // 2 bufs x 32768 halves

  const int tid = threadIdx.x;
  const int lane = tid & 63, wave = tid >> 6;   // wave 0..15
  const int wm = wave >> 2, wn = wave & 3;      // 4M x 4N

  int bid = blockIdx.x;
  int swz = (bid & 7) * (1024 >> 3) + (bid >> 3);
  const int bmBase = (swz >> 4) * 256;
  const int bnBase = (swz & 15) * 256;

  const int s = tid ^ ((tid >> 3) & 3);
  const _Float16* aSrc = A + (size_t)(bmBase + (s >> 2)) * D_DIM + (s & 3) * 8;
  const _Float16* bSrc = Bt + (size_t)(bnBase + (s >> 2)) * D_DIM + (s & 3) * 8;
  const int dstL = tid * 8;

  const int fr = lane & 15, c4 = lane >> 4;
  const int swzc = (c4 ^ ((fr >> 1) & 3)) * 8;
  const int aBase = (wm * 64 + fr) * 32 + swzc;
  const int bBase = (wn * 64 + fr) * 32 + swzc;

  f32x4 acc[4][4];
  #pragma unroll
  for (int i = 0; i < 4; ++i)
    #pragma unroll
    for (int j = 0; j < 4; ++j) acc[i][j] = f32x4{0.f, 0.f, 0.f, 0.f};

  // prologue: stage tile 0; wait own loads; barrier (cross-wave visibility)
  STAGE64(0);
  asm volatile("s_waitcnt vmcnt(0)" ::: "memory");
  __builtin_amdgcn_s_barrier();
  asm volatile("" ::: "memory");

  for (int t = 0; t < KT64 - 1; ++t) BODY64(t, true);
  BODY64(KT64 - 1, false);

  const int crow0 = bmBase + wm * 64 + c4 * 4;
  const int ccol0 = bnBase + wn * 64 + fr;
  #pragma unroll
  for (int mi = 0; mi < 4; ++mi)
    #pragma unroll
    for (int nj = 0; nj < 4; ++nj) {
      int col = ccol0 + nj * 16;
      float lb = latent_bias[col];
      #pragma unroll
      for (int r = 0; r < 4; ++r)
        C[(size_t)(crow0 + mi * 16 + r) * D_DIM + col] =
            (_Float16)(acc[mi][nj][r] + lb);
    }
}

// ------------- fused two-level-histogram top-k + fp64 rescue ---------------
// acts fp16 (quantization +-0.0625 at |v|<256); MARGIN=0.25 covers GEMM
// error (~0.16, 6-sigma) + quantization. Coarse 256 x 4.0 -> rank-refined
// fine 256 x 0.015625 -> T64 bracket [Tlo,Thi). Members: v > Thi+M
// (provably in exact top-64, < 64 of them). Zone: [Tlo-M, Thi+M]. Fast
// path: |zone| == need -> emit. Else fp64 dots (wave-per-candidate).

__global__ __launch_bounds__(256) void topk_full(
    const _Float16* __restrict__ acts, const float* __restrict__ x,
    const float* __restrict__ WT, const float* __restrict__ pre_bias,
    const float* __restrict__ latent_bias, float* __restrict__ vals,
    int* __restrict__ idxs) {
  const int row = blockIdx.x;
  const int tid = threadIdx.x;
  const int lane = tid & 63, wave = tid >> 6;
  __shared__ int hist[256];
  __shared__ int suf[256];
  __shared__ int sred[8];
  __shared__ int ambL[128];
  __shared__ double exv[128];
  const _Float16* arow = acts + (size_t)row * D_DIM;
  float fv[16];
  {
    half8 h0 = *(const half8*)(arow + tid * 8);
    half8 h1 = *(const half8*)(arow + 2048 + tid * 8);
    #pragma unroll
    for (int j = 0; j < 8; ++j) {
      fv[j] = (float)h0[j];
      fv[8 + j] = (float)h1[j];
    }
  }
  // ---- coarse pass ----
  hist[tid] = 0;
  __syncthreads();
  #pragma unroll
  for (int e = 0; e < 16; ++e) {
    int b = (int)((fv[e] + 512.0f) * 0.25f);
    b = b < 0 ? 0 : (b > 255 ? 255 : b);
    atomicAdd(&hist[b], 1);
  }
  __syncthreads();
  int c = hist[tid];
  int sfx = c;
  #pragma unroll
  for (int off = 1; off < 64; off <<= 1) {
    int y = __shfl_down(sfx, off);
    if (lane + off < 64) sfx += y;
  }
  if (lane == 0) sred[wave] = sfx;
  __syncthreads();
  {
    int after = 0;
    for (int w = wave + 1; w < 4; ++w) after += sred[w];
    sfx += after;  // count of values in bins >= tid
  }
  suf[tid] = sfx;
  int cnd = (sfx >= TOPK) ? tid : -1;
  #pragma unroll
  for (int off = 32; off; off >>= 1) {
    int y = __shfl_down(cnd, off);
    cnd = y > cnd ? y : cnd;
  }
  if (lane == 0) sred[4 + wave] = cnd;
  __syncthreads();
  int cb;
  {
    int m0 = sred[4] > sred[5] ? sred[4] : sred[5];
    int m1 = sred[6] > sred[7] ? sred[6] : sred[7];
    cb = m0 > m1 ? m0 : m1;  // exists: suffix(0) = 4096 >= 64
  }
  const int S_above = (cb < 255) ? suf[cb + 1] : 0;
  const int rrank = TOPK - S_above;  // in [1, count(cb)]
  const float Clo = cb * 4.0f - 512.0f;
  // ---- fine pass (reuse hist/sred) ----
  __syncthreads();
  hist[tid] = 0;
  __syncthreads();
  #pragma unroll
  for (int e = 0; e < 16; ++e) {
    int bc = (int)((fv[e] + 512.0f) * 0.25f);
    bc = bc < 0 ? 0 : (bc > 255 ? 255 : bc);
    if (bc == cb) {
      int fb = (int)((fv[e] - Clo) * 64.0f);
      fb = fb < 0 ? 0 : (fb > 255 ? 255 : fb);
      atomicAdd(&hist[fb], 1);
    }
  }
  __syncthreads();
  int cf = hist[tid];
  int sfx2 = cf;
  #pragma unroll
  for (int off = 1; off < 64; off <<= 1) {
    int y = __shfl_down(sfx2, off);
    if (lane + off < 64) sfx2 += y;
  }
  if (lane == 0) sred[wave] = sfx2;
  __syncthreads();
  {
    int after = 0;
    for (int w = wave + 1; w < 4; ++w) after += sred[w];
    sfx2 += after;
  }
  int cnd2 = (sfx2 >= rrank) ? tid : -1;
  #pragma unroll
  for (int off = 32; off; off >>= 1) {
    int y = __shfl_down(cnd2, off);
    cnd2 = y > cnd2 ? y : cnd2;
  }
  if (lane == 0) sred[4 + wave] = cnd2;
  __syncthreads();
  int fb;
  {
    int m0 = sred[4] > sred[5] ? sred[4] : sred[5];
    int m1 = sred[6] > sred[7] ? sred[6] : sred[7];
    fb = m0 > m1 ? m0 : m1;  // exists: fine suffix(0) = count(cb) >= rrank
  }
  const float Tlo = (cb == 0 && fb == 0) ? -1e30f : (Clo + fb * 0.015625f);
  const float Thi =
      (cb == 255 && fb == 255) ? 1e30f : (Clo + (fb + 1) * 0.015625f);
  const float vhi = Thi + MARGIN;
  const float vlo = Tlo - MARGIN;
  // ---- classify + emit ----
  int mC = 0, aC = 0;
  #pragma unroll
  for (int i = 0; i < 16; ++i) {
    float v = fv[i];
    if (v > vhi) ++mC;
    else if (v >= vlo) ++aC;
  }
  int xs = mC | (aC << 16);
  #pragma unroll
  for (int off = 1; off < 64; off <<= 1) {
    int y = __shfl_up(xs, off);
    if (lane >= off) xs += y;
  }
  __syncthreads();  // sred reuse
  if (lane == 63) sred[wave] = xs;
  __syncthreads();
  int base = 0;
  for (int w = 0; w < 4; ++w)
    if (w < wave) base += sred[w];
  int tot = sred[0] + sred[1] + sred[2] + sred[3];
  int incl = base + xs;
  int mp = (incl & 0xffff) - mC;
  int ap = (incl >> 16) - aC;
  int mTot = tot & 0xffff, aTot = tot >> 16;
  const int need = TOPK - mTot;      // >= 1 provably
  const bool fast = (aTot == need);  // zone exactly fills the remainder
  #pragma unroll
  for (int e = 0; e < 16; ++e) {
    float v = fv[e];
    int d = (e < 8) ? (tid * 8 + e) : (2048 + tid * 8 + (e - 8));
    if (v > vhi) {
      vals[(size_t)row * TOPK + mp] = fmaxf(v, 0.0f);
      idxs[(size_t)row * TOPK + mp] = d;
      ++mp;
    } else if (v >= vlo) {
      if (fast) {
        vals[(size_t)row * TOPK + mTot + ap] = fmaxf(v, 0.0f);
        idxs[(size_t)row * TOPK + mTot + ap] = d;
      } else if (ap < 128) {
        ambL[ap] = d;
      }
      ++ap;
    }
  }
  if (fast) return;
  // ---- fused fp64 rescue ----
  __syncthreads();  // ambL visible block-wide
  const int sN = aTot > 128 ? 128 : aTot;
  const float* xr = x + (size_t)row * D_DIM;
  for (int cc = wave; cc < sN; cc += 4) {
    int d = ambL[cc];
    const float* wrow = WT + (size_t)d * D_DIM;
    double acc = 0.0;
    #pragma unroll 4
    for (int t = 0; t < 16; ++t) {
      int k0 = t * 256 + lane * 4;
      float4 xv = *(const float4*)(xr + k0);
      float4 pv = *(const float4*)(pre_bias + k0);
      float4 wv = *(const float4*)(wrow + k0);
      acc = fma((double)xv.x - (double)pv.x, (double)wv.x, acc);
      acc = fma((double)xv.y - (double)pv.y, (double)wv.y, acc);
      acc = fma((double)xv.z - (double)pv.z, (double)wv.z, acc);
      acc = fma((double)xv.w - (double)pv.w, (double)wv.w, acc);
    }
    #pragma unroll
    for (int off = 32; off; off >>= 1) acc += __shfl_down(acc, off);
    if (lane == 0) exv[cc] = acc + (double)latent_bias[d];
  }
  __syncthreads();
  if (tid == 0) {
    for (int t = 0; t < need; ++t) {
      double best = -1.0e300; int besti = 1 << 30; int bestc = -1;
      for (int cc = 0; cc < sN; ++cc) {
        double v = exv[cc];
        int d = ambL[cc];
        if (v > best || (v == best && d < besti)) {
          best = v; besti = d; bestc = cc;
        }
      }
      vals[(size_t)row * TOPK + mTot + t] = fmaxf((float)best, 0.0f);
      idxs[(size_t)row * TOPK + mTot + t] = besti;
      exv[bestc] = -1.0e300;
    }
  }
}

// ----------------------------- reconstruct ---------------------------------

__global__ __launch_bounds__(256) void reconstruct(
    const unsigned short* __restrict__ Wd, const float* __restrict__ vals,
    const int* __restrict__ idxs, const float* __restrict__ pre_bias,
    float* __restrict__ out) {
  const int bid = blockIdx.x;
  const int cb = bid & 7, rowblk = bid >> 3;
  const int tid = threadIdx.x, lane = tid & 63, wave = tid >> 6;
  const int row = rowblk * 4 + wave;
  const int col0 = cb * 512 + lane * 8;
  __shared__ float sval[256];
  __shared__ int sidx[256];
  sval[tid] = vals[(size_t)(rowblk * 4 + (tid >> 6)) * TOPK + (tid & 63)];
  sidx[tid] = idxs[(size_t)(rowblk * 4 + (tid >> 6)) * TOPK + (tid & 63)];
  __syncthreads();
  float acc[8];
  float4 p0 = *(const float4*)(pre_bias + col0);
  float4 p1 = *(const float4*)(pre_bias + col0 + 4);
  acc[0] = p0.x; acc[1] = p0.y; acc[2] = p0.z; acc[3] = p0.w;
  acc[4] = p1.x; acc[5] = p1.y; acc[6] = p1.z; acc[7] = p1.w;
  #pragma unroll 4
  for (int k = 0; k < TOPK; ++k) {
    float v = sval[wave * 64 + k];
    int d = sidx[wave * 64 + k];
    ushort8 w = *(const ushort8*)(Wd + (size_t)d * D_DIM + col0);
    #pragma unroll
    for (int j = 0; j < 8; ++j)
      acc[j] = fmaf(v, __uint_as_float(((unsigned)w[j]) << 16), acc[j]);
  }
  float4 o0 = {acc[0], acc[1], acc[2], acc[3]};
  float4 o1 = {acc[4], acc[5], acc[6], acc[7]};
  *(float4*)(out + (size_t)row * D_DIM + col0) = o0;
  *(float4*)(out + (size_t)row * D_DIM + col0 + 4) = o1;
}

// ------------------------------- launcher ----------------------------------

extern "C" void kernel_launch(void* const* d_in, const int* in_sizes, int n_in,
                              void* d_out, int out_size, void* d_ws,
                              size_t ws_size, hipStream_t stream) {
  const float* x           = (const float*)d_in[0];
  // d_in[1] = ema_frequency_counter (unused by reference)
  const float* W_enc       = (const float*)d_in[2];
  const float* W_dec       = (const float*)d_in[3];
  const float* pre_bias    = (const float*)d_in[4];
  const float* latent_bias = (const float*)d_in[5];
  float* out = (float*)d_out;
  // fp16 acts alias d_out's first half; fully consumed by topk_full before
  // reconstruct overwrites all of out.
  _Float16* actsH = (_Float16*)d_out;
  char* ws = (char*)d_ws;
  size_t off = 0;
  auto alloc = [&](size_t bytes) {
    size_t o = off;
    off = (off + bytes + 255) & ~(size_t)255;
    return o;
  };
  _Float16* Xh        = (_Float16*)(ws + alloc((size_t)B_ROWS * D_DIM * 2));
  _Float16* WhT       = (_Float16*)(ws + alloc((size_t)D_DIM * D_DIM * 2));
  float* WT           = (float*)(ws + alloc((size_t)D_DIM * D_DIM * 4));
  unsigned short* Wd  = (unsigned short*)(ws + alloc((size_t)D_DIM * D_DIM * 2));
  float* vals         = (float*)(ws + alloc((size_t)B_ROWS * TOPK * 4));
  int* idxs           = (int*)(ws + alloc((size_t)B_ROWS * TOPK * 4));
  (void)ws_size; (void)in_sizes; (void)n_in; (void)out_size;

  // allow 128KB dynamic LDS for the GEMM (cheap, deterministic, idempotent)
  (void)hipFuncSetAttribute((const void*)gemm_f16,
                            hipFuncAttributeMaxDynamicSharedMemorySize,
                            131072);

  preprocess<<<45056, 256, 0, stream>>>(x, pre_bias, W_enc, W_dec,
                                        Xh, WhT, WT, Wd);
  gemm_f16<<<(B_ROWS / 256) * (D_DIM / 256), 1024, 131072, stream>>>(
      Xh, WhT, latent_bias, actsH);
  topk_full<<<B_ROWS, 256, 0, stream>>>(actsH, x, WT, pre_bias, latent_bias,
                                        vals, idxs);
  reconstruct<<<(B_ROWS / 4) * 8, 256, 0, stream>>>(Wd, vals, idxs, pre_bias,
                                                    out);
}